// Round 1
// baseline (300.014 us; speedup 1.0000x reference)
//
#include <hip/hip_runtime.h>

// Problem constants
#define BB 16
#define CC 256
#define II 128
#define NN 2048            // H*W = 64*32
#define BN_EPS 1e-5f

// Workspace layout (in floats)
#define PROJSZ    (BB * II * NN)                  // 4,194,304 per projection
#define OFF_THETA 0
#define OFF_PHI   (PROJSZ)
#define OFF_G     (2 * PROJSZ)
#define MPARTSZ   (4 * BB * II * II)              // 1,048,576
#define OFF_MPART (3 * PROJSZ)
#define OFF_M     (OFF_MPART + MPARTSZ)           // 262,144
#define OFF_R     (OFF_M + BB * II * II)          // 524,288
#define OFF_Z     (OFF_R + BB * CC * II)          // 8,388,608
#define OFF_STATS (OFF_Z + BB * CC * NN)          // 512

#define MICRO_FMA(av, bv) \
    acc[0][0] += av.x * bv.x; acc[0][1] += av.x * bv.y; acc[0][2] += av.x * bv.z; acc[0][3] += av.x * bv.w; \
    acc[1][0] += av.y * bv.x; acc[1][1] += av.y * bv.y; acc[1][2] += av.y * bv.z; acc[1][3] += av.y * bv.w; \
    acc[2][0] += av.z * bv.x; acc[2][1] += av.z * bv.y; acc[2][2] += av.z * bv.z; acc[2][3] += av.z * bv.w; \
    acc[3][0] += av.w * bv.x; acc[3][1] += av.w * bv.y; acc[3][2] += av.w * bv.z; acc[3][3] += av.w * bv.w;

// ---------------------------------------------------------------------------
// K1: fused projection GEMM. Wcat [384,256] @ X [256, B*N] -> proj[3][B][128][N]
// rows 0-127 = theta, 128-255 = phi, 256-383 = g
// ---------------------------------------------------------------------------
__global__ __launch_bounds__(256) void proj_gemm(
    const float* __restrict__ x,
    const float* __restrict__ theta_w, const float* __restrict__ theta_b,
    const float* __restrict__ phi_w,   const float* __restrict__ phi_b,
    const float* __restrict__ g_w,     const float* __restrict__ g_b,
    float* __restrict__ proj)
{
    __shared__ float As[32][68];   // [k][m], pad 4 keeps float4 reads aligned
    __shared__ float Bs[32][64];   // [k][n]
    const int tid = threadIdx.x;
    const int colBase = blockIdx.x * 64;        // 0..32767 (global col = b*N + n)
    const int rowBase = blockIdx.y * 64;        // 0..383
    const int b    = colBase >> 11;             // / 2048
    const int n0   = colBase & (NN - 1);
    const int which = rowBase >> 7;             // 0 theta, 1 phi, 2 g
    const float* wsel = (which == 0) ? theta_w : (which == 1 ? phi_w : g_w);
    const float* bsel = (which == 0) ? theta_b : (which == 1 ? phi_b : g_b);
    const int rloc = rowBase & (II - 1);
    const int a_r = tid >> 2;                   // 0..63
    const int a_k = (tid & 3) * 8;              // 0,8,16,24
    const int b_n = tid & 63;
    const int b_k = tid >> 6;                   // 0..3
    const int ty = tid >> 4, tx = tid & 15;
    float acc[4][4] = {};

    const float* xb = x + (size_t)b * CC * NN + n0 + b_n;
    const float* ap0 = wsel + (size_t)(rloc + a_r) * CC + a_k;

    for (int k0 = 0; k0 < CC; k0 += 32) {
        #pragma unroll
        for (int j = 0; j < 8; ++j) As[a_k + j][a_r] = ap0[k0 + j];
        #pragma unroll
        for (int kk = 0; kk < 8; ++kk) {
            const int k = b_k + kk * 4;
            Bs[k][b_n] = xb[(size_t)(k0 + k) * NN];
        }
        __syncthreads();
        #pragma unroll
        for (int k = 0; k < 32; ++k) {
            const float4 av = *reinterpret_cast<const float4*>(&As[k][ty * 4]);
            const float4 bv = *reinterpret_cast<const float4*>(&Bs[k][tx * 4]);
            MICRO_FMA(av, bv)
        }
        __syncthreads();
    }
    float* dst = proj + (size_t)which * PROJSZ + (size_t)b * II * NN;
    #pragma unroll
    for (int ii = 0; ii < 4; ++ii) {
        const int rl = rloc + ty * 4 + ii;
        const float bias = bsel[rl];
        float4 o = { acc[ii][0] + bias, acc[ii][1] + bias,
                     acc[ii][2] + bias, acc[ii][3] + bias };
        *reinterpret_cast<float4*>(&dst[(size_t)rl * NN + n0 + tx * 4]) = o;
    }
}

// ---------------------------------------------------------------------------
// K2: per-batch Gram M[i][j] = sum_n Phi[i][n] * G[j][n], 4-way K-split -> partials
// ---------------------------------------------------------------------------
__global__ __launch_bounds__(256) void m_partial(
    const float* __restrict__ phi, const float* __restrict__ g,
    float* __restrict__ mpart)
{
    __shared__ float Ps[32][68];
    __shared__ float Gs[32][68];
    const int tid = threadIdx.x;
    const int jBase = blockIdx.x * 64;
    const int iBase = blockIdx.y * 64;
    const int b  = blockIdx.z >> 2;
    const int ks = blockIdx.z & 3;
    const int a_r = tid >> 2;
    const int a_k = (tid & 3) * 8;
    const int ty = tid >> 4, tx = tid & 15;
    float acc[4][4] = {};
    const float* pp = phi + ((size_t)b * II + iBase + a_r) * NN + a_k;
    const float* gp = g   + ((size_t)b * II + jBase + a_r) * NN + a_k;

    const int kEnd = ks * 512 + 512;
    for (int k0 = ks * 512; k0 < kEnd; k0 += 32) {
        #pragma unroll
        for (int j = 0; j < 8; ++j) Ps[a_k + j][a_r] = pp[k0 + j];
        #pragma unroll
        for (int j = 0; j < 8; ++j) Gs[a_k + j][a_r] = gp[k0 + j];
        __syncthreads();
        #pragma unroll
        for (int k = 0; k < 32; ++k) {
            const float4 av = *reinterpret_cast<const float4*>(&Ps[k][ty * 4]);
            const float4 bv = *reinterpret_cast<const float4*>(&Gs[k][tx * 4]);
            MICRO_FMA(av, bv)
        }
        __syncthreads();
    }
    float* dst = mpart + (((size_t)ks * BB + b) * II + iBase) * II + jBase;
    #pragma unroll
    for (int ii = 0; ii < 4; ++ii) {
        float4 o = { acc[ii][0], acc[ii][1], acc[ii][2], acc[ii][3] };
        *reinterpret_cast<float4*>(&dst[(size_t)(ty * 4 + ii) * II + tx * 4]) = o;
    }
}

// ---------------------------------------------------------------------------
// K3a: reduce 4 K-split partials -> M[b][i][j]
// ---------------------------------------------------------------------------
__global__ __launch_bounds__(256) void m_reduce(
    const float* __restrict__ mpart, float* __restrict__ M)
{
    const int i = blockIdx.x * 256 + threadIdx.x;   // float4 index, 0..65535
    const size_t S = (size_t)BB * II * II / 4;
    const float4* p = reinterpret_cast<const float4*>(mpart);
    const float4 a = p[i], b = p[i + S], c = p[i + 2 * S], d = p[i + 3 * S];
    float4 o = { a.x + b.x + c.x + d.x, a.y + b.y + c.y + d.y,
                 a.z + b.z + c.z + d.z, a.w + b.w + c.w + d.w };
    reinterpret_cast<float4*>(M)[i] = o;
}

// ---------------------------------------------------------------------------
// K3b: R[b][c][e] = (1/N) * sum_d Ww[c][d] * M[b][e][d]
// ---------------------------------------------------------------------------
__global__ __launch_bounds__(256) void r_gemm(
    const float* __restrict__ Ww, const float* __restrict__ M,
    float* __restrict__ R)
{
    __shared__ float As[32][68];   // [d][c]
    __shared__ float Bs[32][68];   // [d][e]
    const int tid = threadIdx.x;
    const int eBase = blockIdx.x * 64;   // 0..1
    const int cBase = blockIdx.y * 64;   // 0..3
    const int b = blockIdx.z;
    const int a_r = tid >> 2;
    const int a_k = (tid & 3) * 8;
    const int ty = tid >> 4, tx = tid & 15;
    float acc[4][4] = {};
    const float* wp = Ww + (size_t)(cBase + a_r) * II + a_k;
    const float* mp = M + ((size_t)b * II + eBase + a_r) * II + a_k;

    for (int k0 = 0; k0 < II; k0 += 32) {
        #pragma unroll
        for (int j = 0; j < 8; ++j) As[a_k + j][a_r] = wp[k0 + j];
        #pragma unroll
        for (int j = 0; j < 8; ++j) Bs[a_k + j][a_r] = mp[k0 + j];
        __syncthreads();
        #pragma unroll
        for (int k = 0; k < 32; ++k) {
            const float4 av = *reinterpret_cast<const float4*>(&As[k][ty * 4]);
            const float4 bv = *reinterpret_cast<const float4*>(&Bs[k][tx * 4]);
            MICRO_FMA(av, bv)
        }
        __syncthreads();
    }
    float* dst = R + ((size_t)b * CC + cBase) * II + eBase;
    const float sc = 1.0f / (float)NN;
    #pragma unroll
    for (int ii = 0; ii < 4; ++ii) {
        float4 o = { acc[ii][0] * sc, acc[ii][1] * sc, acc[ii][2] * sc, acc[ii][3] * sc };
        *reinterpret_cast<float4*>(&dst[(size_t)(ty * 4 + ii) * II + tx * 4]) = o;
    }
}

// ---------------------------------------------------------------------------
// K4: z[b][c][n] = sum_e R[b][c][e] * Theta[b][e][n] + Wb[c]
// ---------------------------------------------------------------------------
__global__ __launch_bounds__(256) void z_gemm(
    const float* __restrict__ R, const float* __restrict__ theta,
    const float* __restrict__ Wb, float* __restrict__ z)
{
    __shared__ float As[32][68];   // [e][c]
    __shared__ float Bs[32][64];   // [e][n]
    const int tid = threadIdx.x;
    const int n0 = blockIdx.x * 64;
    const int cBase = blockIdx.y * 64;
    const int b = blockIdx.z;
    const int a_r = tid >> 2;
    const int a_k = (tid & 3) * 8;
    const int b_n = tid & 63;
    const int b_k = tid >> 6;
    const int ty = tid >> 4, tx = tid & 15;
    float acc[4][4] = {};
    const float* rp = R + ((size_t)b * CC + cBase + a_r) * II + a_k;
    const float* tp = theta + (size_t)b * II * NN + n0 + b_n;

    for (int k0 = 0; k0 < II; k0 += 32) {
        #pragma unroll
        for (int j = 0; j < 8; ++j) As[a_k + j][a_r] = rp[k0 + j];
        #pragma unroll
        for (int kk = 0; kk < 8; ++kk) {
            const int k = b_k + kk * 4;
            Bs[k][b_n] = tp[(size_t)(k0 + k) * NN];
        }
        __syncthreads();
        #pragma unroll
        for (int k = 0; k < 32; ++k) {
            const float4 av = *reinterpret_cast<const float4*>(&As[k][ty * 4]);
            const float4 bv = *reinterpret_cast<const float4*>(&Bs[k][tx * 4]);
            MICRO_FMA(av, bv)
        }
        __syncthreads();
    }
    float* dst = z + (size_t)b * CC * NN;
    #pragma unroll
    for (int ii = 0; ii < 4; ++ii) {
        const int c = cBase + ty * 4 + ii;
        const float bias = Wb[c];
        float4 o = { acc[ii][0] + bias, acc[ii][1] + bias,
                     acc[ii][2] + bias, acc[ii][3] + bias };
        *reinterpret_cast<float4*>(&dst[(size_t)c * NN + n0 + tx * 4]) = o;
    }
}

// ---------------------------------------------------------------------------
// K5: per-channel mean / inv-std over (B, N) — training-mode batch stats
// ---------------------------------------------------------------------------
__global__ __launch_bounds__(256) void bn_stats(
    const float* __restrict__ z, float* __restrict__ stats)
{
    const int c = blockIdx.x;
    const int tid = threadIdx.x;
    float s = 0.f, sq = 0.f;
    for (int b = 0; b < BB; ++b) {
        const float* p = z + (size_t)b * CC * NN + (size_t)c * NN;
        for (int t = tid; t < NN; t += 256) {
            const float v = p[t];
            s += v; sq += v * v;
        }
    }
    #pragma unroll
    for (int off = 32; off > 0; off >>= 1) {
        s  += __shfl_down(s, off);
        sq += __shfl_down(sq, off);
    }
    __shared__ float ls[4], lq[4];
    const int wid = tid >> 6, lane = tid & 63;
    if (lane == 0) { ls[wid] = s; lq[wid] = sq; }
    __syncthreads();
    if (tid == 0) {
        const float S = ls[0] + ls[1] + ls[2] + ls[3];
        const float Q = lq[0] + lq[1] + lq[2] + lq[3];
        const float mean = S / 32768.f;
        const float var  = Q / 32768.f - mean * mean;
        stats[c]      = mean;
        stats[CC + c] = rsqrtf(var + BN_EPS);
    }
}

// ---------------------------------------------------------------------------
// K6: out = (z - mean) * istd * gamma + beta + x   (float4 elementwise)
// ---------------------------------------------------------------------------
__global__ __launch_bounds__(256) void bn_apply(
    const float4* __restrict__ z4, const float4* __restrict__ x4,
    float4* __restrict__ out4, const float* __restrict__ stats,
    const float* __restrict__ gamma, const float* __restrict__ beta)
{
    const int i = blockIdx.x * 256 + threadIdx.x;   // float4 index
    const int c = (i >> 9) & (CC - 1);              // (i*4 / 2048) % 256
    const float mean = stats[c], istd = stats[CC + c];
    const float gm = gamma[c] * istd;
    const float bt = beta[c] - mean * gm;
    const float4 zv = z4[i];
    const float4 xv = x4[i];
    float4 o = { zv.x * gm + bt + xv.x, zv.y * gm + bt + xv.y,
                 zv.z * gm + bt + xv.z, zv.w * gm + bt + xv.w };
    out4[i] = o;
}

// ---------------------------------------------------------------------------
extern "C" void kernel_launch(void* const* d_in, const int* in_sizes, int n_in,
                              void* d_out, int out_size, void* d_ws, size_t ws_size,
                              hipStream_t stream) {
    const float* x       = (const float*)d_in[0];
    const float* g_w     = (const float*)d_in[1];
    const float* g_b     = (const float*)d_in[2];
    const float* theta_w = (const float*)d_in[3];
    const float* theta_b = (const float*)d_in[4];
    const float* phi_w   = (const float*)d_in[5];
    const float* phi_b   = (const float*)d_in[6];
    const float* W_w     = (const float*)d_in[7];
    const float* W_b     = (const float*)d_in[8];
    const float* bn_g    = (const float*)d_in[9];
    const float* bn_bt   = (const float*)d_in[10];
    float* ws  = (float*)d_ws;
    float* out = (float*)d_out;

    // 1. Projections: theta/phi/g = w @ x + b   [B][128][N] each
    proj_gemm<<<dim3(512, 6), 256, 0, stream>>>(
        x, theta_w, theta_b, phi_w, phi_b, g_w, g_b, ws);

    // 2. M[b] = Phi_b @ G_b^T  (K-split over N into 4 partials)
    m_partial<<<dim3(2, 2, 64), 256, 0, stream>>>(
        ws + OFF_PHI, ws + OFF_G, ws + OFF_MPART);

    // 3a. Reduce partials
    m_reduce<<<dim3(256), 256, 0, stream>>>(ws + OFF_MPART, ws + OFF_M);

    // 3b. R[b] = W_w @ M_b^T / N
    r_gemm<<<dim3(2, 4, 16), 256, 0, stream>>>(W_w, ws + OFF_M, ws + OFF_R);

    // 4. z[b] = R_b @ Theta_b + W_b
    z_gemm<<<dim3(32, 4, 16), 256, 0, stream>>>(
        ws + OFF_R, ws + OFF_THETA, W_b, ws + OFF_Z);

    // 5. BN statistics
    bn_stats<<<dim3(256), 256, 0, stream>>>(ws + OFF_Z, ws + OFF_STATS);

    // 6. Normalize + residual
    bn_apply<<<dim3(8192), 256, 0, stream>>>(
        (const float4*)(ws + OFF_Z), (const float4*)x, (float4*)out,
        ws + OFF_STATS, bn_g, bn_bt);
}

// Round 2
// 297.040 us; speedup vs baseline: 1.0100x; 1.0100x over previous
//
#include <hip/hip_runtime.h>

typedef unsigned int uint;
typedef unsigned short ushort;
typedef __attribute__((ext_vector_type(8))) short bf16x8;
typedef __attribute__((ext_vector_type(4))) float f32x4;

#define BB 16
#define CC 256
#define II 128
#define NN 2048
#define BN_EPS 1e-5f

// ---- workspace layout (float offsets) ----
#define OFF_GRAM  0                       // [16][256][256] f32 (zeroed)
#define OFF_S     1048576                 // [16][256] f32 row sums (zeroed)
#define OFF_CP    1052672                 // [16][256] f32 c' bias (zeroed)
#define OFF_STAT  1056768                 // [512] f32 sum/sumsq acc (zeroed)
#define OFF_STAT2 1057280                 // [512] f32 mean/istd
#define OFF_U     1057792                 // [16][128]
#define OFF_V     1059840                 // [16][128]
#define OFF_T1    1061888                 // [16][128][256]
#define OFF_KB    1586176                 // [16][128][128]
#define OFF_T2    1848320                 // [16][256][128]
#define OFF_FLOAT_END 2372608
// ushort regions follow (offsets in ushorts from SBF base)
#define USZ_SBF   (16*256*256)            // 1,048,576
#define USZ_X     (16*256*2048)           // 8,388,608

static __device__ __forceinline__ ushort f2bf(float f) {
    uint u = __float_as_uint(f);
    return (ushort)((u + 0x7FFFu + ((u >> 16) & 1u)) >> 16);
}
static __device__ __forceinline__ float bflo(uint w) { return __uint_as_float(w << 16); }
static __device__ __forceinline__ float bfhi(uint w) { return __uint_as_float(w & 0xFFFF0000u); }

#define MICRO_FMA(av, bv) \
    acc[0][0] += av.x * bv.x; acc[0][1] += av.x * bv.y; acc[0][2] += av.x * bv.z; acc[0][3] += av.x * bv.w; \
    acc[1][0] += av.y * bv.x; acc[1][1] += av.y * bv.y; acc[1][2] += av.y * bv.z; acc[1][3] += av.y * bv.w; \
    acc[2][0] += av.z * bv.x; acc[2][1] += av.z * bv.y; acc[2][2] += av.z * bv.z; acc[2][3] += av.z * bv.w; \
    acc[3][0] += av.w * bv.x; acc[3][1] += av.w * bv.y; acc[3][2] += av.w * bv.z; acc[3][3] += av.w * bv.w;

// ---------------------------------------------------------------------------
// K0: x (fp32 [b][c][n]) -> xbf (bf16 same layout) + xT (bf16 [b][n][c])
// ---------------------------------------------------------------------------
__global__ __launch_bounds__(256) void convert_transpose(
    const float* __restrict__ x, ushort* __restrict__ xbf, ushort* __restrict__ xT)
{
    __shared__ ushort tile[64][72];
    const int t = threadIdx.x;
    const int b = blockIdx.z, c0 = blockIdx.y * 64, n0 = blockIdx.x * 64;
    const int row = t & 63, ch = t >> 6;
    const size_t srcIdx = ((size_t)(b * CC + c0 + row)) * NN + n0 + ch * 16;
    const float4* sp = (const float4*)(x + srcIdx);
    float4 v0 = sp[0], v1 = sp[1], v2 = sp[2], v3 = sp[3];
    ushort a[16];
    a[0]=f2bf(v0.x); a[1]=f2bf(v0.y); a[2]=f2bf(v0.z); a[3]=f2bf(v0.w);
    a[4]=f2bf(v1.x); a[5]=f2bf(v1.y); a[6]=f2bf(v1.z); a[7]=f2bf(v1.w);
    a[8]=f2bf(v2.x); a[9]=f2bf(v2.y); a[10]=f2bf(v2.z); a[11]=f2bf(v2.w);
    a[12]=f2bf(v3.x); a[13]=f2bf(v3.y); a[14]=f2bf(v3.z); a[15]=f2bf(v3.w);
    uint p[8];
    #pragma unroll
    for (int i = 0; i < 8; ++i) p[i] = (uint)a[2*i] | ((uint)a[2*i+1] << 16);
    uint4* dp = (uint4*)(xbf + srcIdx);
    dp[0] = make_uint4(p[0], p[1], p[2], p[3]);
    dp[1] = make_uint4(p[4], p[5], p[6], p[7]);
    uint* tp = (uint*)&tile[row][ch * 16];
    #pragma unroll
    for (int i = 0; i < 8; ++i) tp[i] = p[i];
    __syncthreads();
    const int trow = t & 63, cch = t >> 6;
    uint q[8];
    #pragma unroll
    for (int i = 0; i < 8; ++i) {
        ushort lo = tile[cch * 16 + 2*i][trow];
        ushort hi = tile[cch * 16 + 2*i + 1][trow];
        q[i] = (uint)lo | ((uint)hi << 16);
    }
    uint4* op = (uint4*)(xT + ((size_t)(b * NN + n0 + trow)) * CC + c0 + cch * 16);
    op[0] = make_uint4(q[0], q[1], q[2], q[3]);
    op[1] = make_uint4(q[4], q[5], q[6], q[7]);
}

// ---------------------------------------------------------------------------
// K1: Gram_b = xbf_b @ xbf_b^T  (bf16 MFMA, 4-way K-split, atomic accumulate)
//     + row sums s_b (jt==0 blocks)
// ---------------------------------------------------------------------------
__global__ __launch_bounds__(256) void gram_mfma(
    const ushort* __restrict__ xbf, float* __restrict__ Gram, float* __restrict__ sArr)
{
    __shared__ ushort As[128][40];
    __shared__ ushort Bs[128][40];
    const int t = threadIdx.x;
    const int jt = blockIdx.x, it = blockIdx.y;
    const int b = blockIdx.z >> 2, kc = blockIdx.z & 3;
    const int iBase = it * 128, jBase = jt * 128;
    const int arow = t >> 1, ah = t & 1;
    const ushort* aSrc = xbf + ((size_t)(b * CC + iBase + arow)) * NN + kc * 512 + ah * 16;
    const ushort* bSrc = xbf + ((size_t)(b * CC + jBase + arow)) * NN + kc * 512 + ah * 16;
    const int lane = t & 63, wid = t >> 6;
    const int mb = (wid >> 1) * 64, nb = (wid & 1) * 64;
    const int lm = lane & 15, q = lane >> 4;
    f32x4 acc[4][4] = {};
    float ssum = 0.f;

    for (int it16 = 0; it16 < 16; ++it16) {
        const uint4* ap = (const uint4*)(aSrc + it16 * 32);
        uint4 a0 = ap[0], a1 = ap[1];
        const uint4* bp = (const uint4*)(bSrc + it16 * 32);
        uint4 b0 = bp[0], b1 = bp[1];
        *(uint4*)&As[arow][ah * 16] = a0;
        *(uint4*)&As[arow][ah * 16 + 8] = a1;
        *(uint4*)&Bs[arow][ah * 16] = b0;
        *(uint4*)&Bs[arow][ah * 16 + 8] = b1;
        if (jt == 0) {
            ssum += bflo(a0.x)+bfhi(a0.x)+bflo(a0.y)+bfhi(a0.y)
                  + bflo(a0.z)+bfhi(a0.z)+bflo(a0.w)+bfhi(a0.w)
                  + bflo(a1.x)+bfhi(a1.x)+bflo(a1.y)+bfhi(a1.y)
                  + bflo(a1.z)+bfhi(a1.z)+bflo(a1.w)+bfhi(a1.w);
        }
        __syncthreads();
        bf16x8 af[4], bf[4];
        #pragma unroll
        for (int mt = 0; mt < 4; ++mt)
            af[mt] = *(const bf16x8*)&As[mb + mt * 16 + lm][q * 8];
        #pragma unroll
        for (int nt = 0; nt < 4; ++nt)
            bf[nt] = *(const bf16x8*)&Bs[nb + nt * 16 + lm][q * 8];
        #pragma unroll
        for (int mt = 0; mt < 4; ++mt)
            #pragma unroll
            for (int nt = 0; nt < 4; ++nt)
                acc[mt][nt] = __builtin_amdgcn_mfma_f32_16x16x32_bf16(af[mt], bf[nt], acc[mt][nt], 0, 0, 0);
        __syncthreads();
    }
    float* gp = Gram + (size_t)b * CC * CC;
    #pragma unroll
    for (int mt = 0; mt < 4; ++mt)
        #pragma unroll
        for (int nt = 0; nt < 4; ++nt)
            #pragma unroll
            for (int r = 0; r < 4; ++r) {
                const int gi = iBase + mb + mt * 16 + q * 4 + r;
                const int gj = jBase + nb + nt * 16 + lm;
                atomicAdd(&gp[gi * CC + gj], acc[mt][nt][r]);
            }
    if (jt == 0) atomicAdd(&sArr[b * CC + iBase + arow], ssum);
}

// ---------------------------------------------------------------------------
// K2a: u_b = Gw @ s_b, v_b = Pw @ s_b
// ---------------------------------------------------------------------------
__global__ __launch_bounds__(256) void uv_kernel(
    const float* __restrict__ Gw, const float* __restrict__ Pw,
    const float* __restrict__ sArr, float* __restrict__ u, float* __restrict__ v)
{
    const int b = blockIdx.x, t = threadIdx.x;
    const float* sp = sArr + b * CC;
    const float* wrow = (t < 128) ? (Gw + (size_t)t * CC) : (Pw + (size_t)(t - 128) * CC);
    float acc = 0.f;
    for (int k = 0; k < CC; ++k) acc += wrow[k] * sp[k];
    if (t < 128) u[b * II + t] = acc;
    else         v[b * II + (t - 128)] = acc;
}

// ---------------------------------------------------------------------------
// K2b: T1_b = Gw @ Gram_b   [128x256], K=256  (fp32, NN-style)
// ---------------------------------------------------------------------------
__global__ __launch_bounds__(256) void t1_gemm(
    const float* __restrict__ Gw, const float* __restrict__ Gram, float* __restrict__ T1)
{
    __shared__ float As[32][68];
    __shared__ float Bs[32][64];
    const int tid = threadIdx.x;
    const int jBase = blockIdx.x * 64, iBase = blockIdx.y * 64, b = blockIdx.z;
    const int a_r = tid >> 2, a_k = (tid & 3) * 8;
    const int b_n = tid & 63, b_k = tid >> 6;
    const int ty = tid >> 4, tx = tid & 15;
    float acc[4][4] = {};
    const float* ap0 = Gw + (size_t)(iBase + a_r) * CC + a_k;
    const float* bp0 = Gram + (size_t)b * CC * CC + jBase + b_n;
    for (int k0 = 0; k0 < CC; k0 += 32) {
        #pragma unroll
        for (int j = 0; j < 8; ++j) As[a_k + j][a_r] = ap0[k0 + j];
        #pragma unroll
        for (int kk = 0; kk < 8; ++kk) {
            const int k = b_k + kk * 4;
            Bs[k][b_n] = bp0[(size_t)(k0 + k) * CC];
        }
        __syncthreads();
        #pragma unroll
        for (int k = 0; k < 32; ++k) {
            const float4 av = *(const float4*)&As[k][ty * 4];
            const float4 bv = *(const float4*)&Bs[k][tx * 4];
            MICRO_FMA(av, bv)
        }
        __syncthreads();
    }
    float* dst = T1 + (size_t)b * II * CC;
    #pragma unroll
    for (int ii = 0; ii < 4; ++ii) {
        float4 o = { acc[ii][0], acc[ii][1], acc[ii][2], acc[ii][3] };
        *(float4*)&dst[(size_t)(iBase + ty * 4 + ii) * CC + jBase + tx * 4] = o;
    }
}

// ---------------------------------------------------------------------------
// K2c: K_b = T1_b @ Pw^T + u pb^T + gb v^T + N gb pb^T   [128x128], K=256 (NT)
// ---------------------------------------------------------------------------
__global__ __launch_bounds__(256) void kb_gemm(
    const float* __restrict__ T1, const float* __restrict__ Pw,
    const float* __restrict__ u, const float* __restrict__ v,
    const float* __restrict__ gb, const float* __restrict__ pb,
    float* __restrict__ Kb)
{
    __shared__ float As[32][68];
    __shared__ float Bs[32][68];
    const int tid = threadIdx.x;
    const int jBase = blockIdx.x * 64, iBase = blockIdx.y * 64, b = blockIdx.z;
    const int a_r = tid >> 2, a_k = (tid & 3) * 8;
    const int ty = tid >> 4, tx = tid & 15;
    float acc[4][4] = {};
    const float* ap0 = T1 + (size_t)b * II * CC + (size_t)(iBase + a_r) * CC + a_k;
    const float* bp0 = Pw + (size_t)(jBase + a_r) * CC + a_k;
    for (int k0 = 0; k0 < CC; k0 += 32) {
        #pragma unroll
        for (int j = 0; j < 8; ++j) As[a_k + j][a_r] = ap0[k0 + j];
        #pragma unroll
        for (int j = 0; j < 8; ++j) Bs[a_k + j][a_r] = bp0[k0 + j];
        __syncthreads();
        #pragma unroll
        for (int k = 0; k < 32; ++k) {
            const float4 av = *(const float4*)&As[k][ty * 4];
            const float4 bv = *(const float4*)&Bs[k][tx * 4];
            MICRO_FMA(av, bv)
        }
        __syncthreads();
    }
    float* dst = Kb + (size_t)b * II * II;
    #pragma unroll
    for (int ii = 0; ii < 4; ++ii) {
        const int gi = iBase + ty * 4 + ii;
        const float ug = u[b * II + gi], gg = gb[gi];
        #pragma unroll
        for (int jj = 0; jj < 4; ++jj) {
            const int gj = jBase + tx * 4 + jj;
            acc[ii][jj] += ug * pb[gj] + gg * (v[b * II + gj] + (float)NN * pb[gj]);
        }
        float4 o = { acc[ii][0], acc[ii][1], acc[ii][2], acc[ii][3] };
        *(float4*)&dst[(size_t)gi * II + jBase + tx * 4] = o;
    }
}

// ---------------------------------------------------------------------------
// K2d: T2_b = Ww @ K_b   [256x128], K=128 (NN)
// ---------------------------------------------------------------------------
__global__ __launch_bounds__(256) void t2_gemm(
    const float* __restrict__ Ww, const float* __restrict__ Kb, float* __restrict__ T2)
{
    __shared__ float As[32][68];
    __shared__ float Bs[32][64];
    const int tid = threadIdx.x;
    const int jBase = blockIdx.x * 64, iBase = blockIdx.y * 64, b = blockIdx.z;
    const int a_r = tid >> 2, a_k = (tid & 3) * 8;
    const int b_n = tid & 63, b_k = tid >> 6;
    const int ty = tid >> 4, tx = tid & 15;
    float acc[4][4] = {};
    const float* ap0 = Ww + (size_t)(iBase + a_r) * II + a_k;
    const float* bp0 = Kb + (size_t)b * II * II + jBase + b_n;
    for (int k0 = 0; k0 < II; k0 += 32) {
        #pragma unroll
        for (int j = 0; j < 8; ++j) As[a_k + j][a_r] = ap0[k0 + j];
        #pragma unroll
        for (int kk = 0; kk < 8; ++kk) {
            const int k = b_k + kk * 4;
            Bs[k][b_n] = bp0[(size_t)(k0 + k) * II];
        }
        __syncthreads();
        #pragma unroll
        for (int k = 0; k < 32; ++k) {
            const float4 av = *(const float4*)&As[k][ty * 4];
            const float4 bv = *(const float4*)&Bs[k][tx * 4];
            MICRO_FMA(av, bv)
        }
        __syncthreads();
    }
    float* dst = T2 + (size_t)b * CC * II;
    #pragma unroll
    for (int ii = 0; ii < 4; ++ii) {
        float4 o = { acc[ii][0], acc[ii][1], acc[ii][2], acc[ii][3] };
        *(float4*)&dst[(size_t)(iBase + ty * 4 + ii) * II + jBase + tx * 4] = o;
    }
}

// ---------------------------------------------------------------------------
// K2f: S_b = T2_b @ Tw / N  -> bf16;  c'_b = T2_b @ tb / N (jt==0 fold)
// ---------------------------------------------------------------------------
__global__ __launch_bounds__(256) void s_gemm(
    const float* __restrict__ T2, const float* __restrict__ Tw,
    const float* __restrict__ tb, float* __restrict__ cprime,
    ushort* __restrict__ Sbf)
{
    __shared__ float As[32][68];
    __shared__ float Bs[32][64];
    const int tid = threadIdx.x;
    const int jBase = blockIdx.x * 64, iBase = blockIdx.y * 64, b = blockIdx.z;
    const int a_r = tid >> 2, a_k = (tid & 3) * 8;
    const int b_n = tid & 63, b_k = tid >> 6;
    const int ty = tid >> 4, tx = tid & 15;
    float acc[4][4] = {};
    float cp = 0.f;
    const float* ap0 = T2 + (size_t)b * CC * II + (size_t)(iBase + a_r) * II + a_k;
    const float* bp0 = Tw + jBase + b_n;
    for (int k0 = 0; k0 < II; k0 += 32) {
        #pragma unroll
        for (int j = 0; j < 8; ++j) {
            const float v = ap0[k0 + j];
            As[a_k + j][a_r] = v;
            if (blockIdx.x == 0) cp += v * tb[k0 + a_k + j];
        }
        #pragma unroll
        for (int kk = 0; kk < 8; ++kk) {
            const int k = b_k + kk * 4;
            Bs[k][b_n] = bp0[(size_t)(k0 + k) * CC];
        }
        __syncthreads();
        #pragma unroll
        for (int k = 0; k < 32; ++k) {
            const float4 av = *(const float4*)&As[k][ty * 4];
            const float4 bv = *(const float4*)&Bs[k][tx * 4];
            MICRO_FMA(av, bv)
        }
        __syncthreads();
    }
    const float sc = 1.0f / (float)NN;
    if (blockIdx.x == 0) atomicAdd(&cprime[b * CC + iBase + a_r], cp * sc);
    ushort* dst = Sbf + (size_t)b * CC * CC;
    #pragma unroll
    for (int ii = 0; ii < 4; ++ii) {
        const int gi = iBase + ty * 4 + ii;
        uint p0 = (uint)f2bf(acc[ii][0] * sc) | ((uint)f2bf(acc[ii][1] * sc) << 16);
        uint p1 = (uint)f2bf(acc[ii][2] * sc) | ((uint)f2bf(acc[ii][3] * sc) << 16);
        uint2 o = { p0, p1 };
        *(uint2*)&dst[(size_t)gi * CC + jBase + tx * 4] = o;
    }
}

// ---------------------------------------------------------------------------
// K3: z_b = S_b @ x_b + c' 1^T  (bf16 MFMA) -> zbf; fused BN partial stats
// ---------------------------------------------------------------------------
__global__ __launch_bounds__(256) void z_mfma(
    const ushort* __restrict__ Sbf, const ushort* __restrict__ xT,
    const float* __restrict__ cprime, ushort* __restrict__ zbf,
    float* __restrict__ statsAcc)
{
    __shared__ ushort As[128][40];
    __shared__ ushort Bs[128][40];
    const int t = threadIdx.x;
    const int n0 = blockIdx.x * 128, ct = blockIdx.y * 128, b = blockIdx.z;
    const int arow = t >> 1, ah = t & 1;
    const ushort* aSrc = Sbf + ((size_t)(b * CC + ct + arow)) * CC + ah * 16;
    const ushort* bSrc = xT + ((size_t)(b * NN + n0 + arow)) * CC + ah * 16;
    const int lane = t & 63, wid = t >> 6;
    const int mb = (wid >> 1) * 64, nb = (wid & 1) * 64;
    const int lm = lane & 15, q = lane >> 4;
    f32x4 acc[4][4] = {};

    for (int k0 = 0; k0 < CC; k0 += 32) {
        const uint4* ap = (const uint4*)(aSrc + k0);
        uint4 a0 = ap[0], a1 = ap[1];
        const uint4* bp = (const uint4*)(bSrc + k0);
        uint4 b0 = bp[0], b1 = bp[1];
        *(uint4*)&As[arow][ah * 16] = a0;
        *(uint4*)&As[arow][ah * 16 + 8] = a1;
        *(uint4*)&Bs[arow][ah * 16] = b0;
        *(uint4*)&Bs[arow][ah * 16 + 8] = b1;
        __syncthreads();
        bf16x8 af[4], bf[4];
        #pragma unroll
        for (int mt = 0; mt < 4; ++mt)
            af[mt] = *(const bf16x8*)&As[mb + mt * 16 + lm][q * 8];
        #pragma unroll
        for (int nt = 0; nt < 4; ++nt)
            bf[nt] = *(const bf16x8*)&Bs[nb + nt * 16 + lm][q * 8];
        #pragma unroll
        for (int mt = 0; mt < 4; ++mt)
            #pragma unroll
            for (int nt = 0; nt < 4; ++nt)
                acc[mt][nt] = __builtin_amdgcn_mfma_f32_16x16x32_bf16(af[mt], bf[nt], acc[mt][nt], 0, 0, 0);
        __syncthreads();
    }
    #pragma unroll
    for (int mt = 0; mt < 4; ++mt) {
        #pragma unroll
        for (int r = 0; r < 4; ++r) {
            const int ci = ct + mb + mt * 16 + q * 4 + r;
            const float cp = cprime[b * CC + ci];
            const size_t zrow = ((size_t)(b * CC + ci)) * NN;
            float s1 = 0.f, q1 = 0.f;
            #pragma unroll
            for (int nt = 0; nt < 4; ++nt) {
                const float val = acc[mt][nt][r] + cp;
                const int tok = n0 + nb + nt * 16 + lm;
                zbf[zrow + tok] = f2bf(val);
                s1 += val; q1 += val * val;
            }
            #pragma unroll
            for (int m = 1; m < 16; m <<= 1) {
                s1 += __shfl_xor(s1, m);
                q1 += __shfl_xor(q1, m);
            }
            if (lm == 0) {
                atomicAdd(&statsAcc[ci], s1);
                atomicAdd(&statsAcc[CC + ci], q1);
            }
        }
    }
}

// ---------------------------------------------------------------------------
// K4: finalize stats
// ---------------------------------------------------------------------------
__global__ __launch_bounds__(256) void bn_finalize(
    const float* __restrict__ statsAcc, float* __restrict__ stats2)
{
    const int c = threadIdx.x;
    const float cnt = (float)(BB * NN);
    const float mean = statsAcc[c] / cnt;
    const float var = statsAcc[CC + c] / cnt - mean * mean;
    stats2[c] = mean;
    stats2[CC + c] = rsqrtf(var + BN_EPS);
}

// ---------------------------------------------------------------------------
// K5: out = (z - mean)*istd*gamma + beta + x
// ---------------------------------------------------------------------------
__global__ __launch_bounds__(256) void bn_apply(
    const ushort* __restrict__ zbf, const float* __restrict__ x,
    float* __restrict__ out, const float* __restrict__ stats2,
    const float* __restrict__ gamma, const float* __restrict__ beta)
{
    const size_t i = (size_t)blockIdx.x * 256 + threadIdx.x;
    const size_t base = i * 8;
    const int c = (int)((base >> 11) & (CC - 1));
    const float mean = stats2[c], istd = stats2[CC + c];
    const float gm = gamma[c] * istd;
    const float bt = beta[c] - mean * gm;
    const uint4 zz = *(const uint4*)(zbf + base);
    const float4 x0 = *(const float4*)(x + base);
    const float4 x1 = *(const float4*)(x + base + 4);
    float4 o0, o1;
    o0.x = bflo(zz.x) * gm + bt + x0.x;  o0.y = bfhi(zz.x) * gm + bt + x0.y;
    o0.z = bflo(zz.y) * gm + bt + x0.z;  o0.w = bfhi(zz.y) * gm + bt + x0.w;
    o1.x = bflo(zz.z) * gm + bt + x1.x;  o1.y = bfhi(zz.z) * gm + bt + x1.y;
    o1.z = bflo(zz.w) * gm + bt + x1.w == 0.f ? bflo(zz.w) * gm + bt + x1.z : bflo(zz.w) * gm + bt + x1.z;
    o1.w = bfhi(zz.w) * gm + bt + x1.w;
    *(float4*)(out + base) = o0;
    *(float4*)(out + base + 4) = o1;
}

// ---------------------------------------------------------------------------
extern "C" void kernel_launch(void* const* d_in, const int* in_sizes, int n_in,
                              void* d_out, int out_size, void* d_ws, size_t ws_size,
                              hipStream_t stream) {
    const float* x    = (const float*)d_in[0];
    const float* g_w  = (const float*)d_in[1];
    const float* g_b  = (const float*)d_in[2];
    const float* th_w = (const float*)d_in[3];
    const float* th_b = (const float*)d_in[4];
    const float* ph_w = (const float*)d_in[5];
    const float* ph_b = (const float*)d_in[6];
    const float* W_w  = (const float*)d_in[7];
    // const float* W_b = (const float*)d_in[8];   // cancels in batch-norm
    const float* bn_g = (const float*)d_in[9];
    const float* bn_bt= (const float*)d_in[10];
    float* wsf = (float*)d_ws;
    float* out = (float*)d_out;

    ushort* SBF = (ushort*)(wsf + OFF_FLOAT_END);
    ushort* XBF = SBF + USZ_SBF;
    ushort* XT  = XBF + USZ_X;
    ushort* ZBF = XT + USZ_X;

    // zero Gram + s + c' + stats accumulators (contiguous)
    hipMemsetAsync(wsf + OFF_GRAM, 0, (size_t)(1048576 + 4096 + 4096 + 512) * 4, stream);

    convert_transpose<<<dim3(32, 4, 16), 256, 0, stream>>>(x, XBF, XT);
    gram_mfma<<<dim3(2, 2, 64), 256, 0, stream>>>(XBF, wsf + OFF_GRAM, wsf + OFF_S);
    uv_kernel<<<dim3(16), 256, 0, stream>>>(g_w, ph_w, wsf + OFF_S, wsf + OFF_U, wsf + OFF_V);
    t1_gemm<<<dim3(4, 2, 16), 256, 0, stream>>>(g_w, wsf + OFF_GRAM, wsf + OFF_T1);
    kb_gemm<<<dim3(2, 2, 16), 256, 0, stream>>>(wsf + OFF_T1, ph_w, wsf + OFF_U, wsf + OFF_V,
                                                g_b, ph_b, wsf + OFF_KB);
    t2_gemm<<<dim3(2, 4, 16), 256, 0, stream>>>(W_w, wsf + OFF_KB, wsf + OFF_T2);
    s_gemm<<<dim3(4, 4, 16), 256, 0, stream>>>(wsf + OFF_T2, th_w, th_b, wsf + OFF_CP, SBF);
    z_mfma<<<dim3(16, 2, 16), 256, 0, stream>>>(SBF, XT, wsf + OFF_CP, ZBF, wsf + OFF_STAT);
    bn_finalize<<<dim3(1), 256, 0, stream>>>(wsf + OFF_STAT, wsf + OFF_STAT2);
    bn_apply<<<dim3(4096), 256, 0, stream>>>(ZBF, x, out, wsf + OFF_STAT2, bn_g, bn_bt);
}

// Round 3
// 229.864 us; speedup vs baseline: 1.3052x; 1.2922x over previous
//
#include <hip/hip_runtime.h>

typedef unsigned int uint;
typedef unsigned short ushort;
typedef __attribute__((ext_vector_type(8))) short bf16x8;
typedef __attribute__((ext_vector_type(4))) float f32x4;

#define BB 16
#define CC 256
#define II 128
#define NN 2048
#define BN_EPS 1e-5f

// ---- workspace layout (float offsets) ---- all buffers are write-once (no zero-init)
#define OFF_GRAM   0            // [16][256][256]
#define OFF_GPART  1048576      // [4][16][256][256]
#define OFF_SPART  5242880      // [4][16][256]
#define OFF_CP     5259264      // [16][256]
#define OFF_STATP  5263360      // [256 slots][512]  (sum[c], sumsq[c])
#define OFF_STAT2  5394432      // [512] mean/istd
#define OFF_U      5394944      // [16][128]
#define OFF_V      5396992      // [16][128]
#define OFF_T1     5399040      // [16][128][256]
#define OFF_KB     5923328      // [16][128][128]
#define OFF_T2     6185472      // [16][256][128]
#define OFF_FEND   6709760
// ushort regions follow
#define USZ_SBF   (16*256*256)
#define USZ_X     (16*256*2048)

static __device__ __forceinline__ ushort f2bf(float f) {
    uint u = __float_as_uint(f);
    return (ushort)((u + 0x7FFFu + ((u >> 16) & 1u)) >> 16);
}
static __device__ __forceinline__ float bflo(uint w) { return __uint_as_float(w << 16); }
static __device__ __forceinline__ float bfhi(uint w) { return __uint_as_float(w & 0xFFFF0000u); }

#define MICRO_FMA(av, bv) \
    acc[0][0] += av.x * bv.x; acc[0][1] += av.x * bv.y; acc[0][2] += av.x * bv.z; acc[0][3] += av.x * bv.w; \
    acc[1][0] += av.y * bv.x; acc[1][1] += av.y * bv.y; acc[1][2] += av.y * bv.z; acc[1][3] += av.y * bv.w; \
    acc[2][0] += av.z * bv.x; acc[2][1] += av.z * bv.y; acc[2][2] += av.z * bv.z; acc[2][3] += av.z * bv.w; \
    acc[3][0] += av.w * bv.x; acc[3][1] += av.w * bv.y; acc[3][2] += av.w * bv.z; acc[3][3] += av.w * bv.w;

// ---------------------------------------------------------------------------
// K0: x (fp32 [b][c][n]) -> xbf (bf16 same layout) + xT (bf16 [b][n][c])
// ---------------------------------------------------------------------------
__global__ __launch_bounds__(256) void convert_transpose(
    const float* __restrict__ x, ushort* __restrict__ xbf, ushort* __restrict__ xT)
{
    __shared__ ushort tile[64][72];
    const int t = threadIdx.x;
    const int b = blockIdx.z, c0 = blockIdx.y * 64, n0 = blockIdx.x * 64;
    const int row = t & 63, ch = t >> 6;
    const size_t srcIdx = ((size_t)(b * CC + c0 + row)) * NN + n0 + ch * 16;
    const float4* sp = (const float4*)(x + srcIdx);
    float4 v0 = sp[0], v1 = sp[1], v2 = sp[2], v3 = sp[3];
    ushort a[16];
    a[0]=f2bf(v0.x); a[1]=f2bf(v0.y); a[2]=f2bf(v0.z); a[3]=f2bf(v0.w);
    a[4]=f2bf(v1.x); a[5]=f2bf(v1.y); a[6]=f2bf(v1.z); a[7]=f2bf(v1.w);
    a[8]=f2bf(v2.x); a[9]=f2bf(v2.y); a[10]=f2bf(v2.z); a[11]=f2bf(v2.w);
    a[12]=f2bf(v3.x); a[13]=f2bf(v3.y); a[14]=f2bf(v3.z); a[15]=f2bf(v3.w);
    uint p[8];
    #pragma unroll
    for (int i = 0; i < 8; ++i) p[i] = (uint)a[2*i] | ((uint)a[2*i+1] << 16);
    uint4* dp = (uint4*)(xbf + srcIdx);
    dp[0] = make_uint4(p[0], p[1], p[2], p[3]);
    dp[1] = make_uint4(p[4], p[5], p[6], p[7]);
    uint* tp = (uint*)&tile[row][ch * 16];
    #pragma unroll
    for (int i = 0; i < 8; ++i) tp[i] = p[i];
    __syncthreads();
    const int trow = t & 63, cch = t >> 6;
    uint q[8];
    #pragma unroll
    for (int i = 0; i < 8; ++i) {
        ushort lo = tile[cch * 16 + 2*i][trow];
        ushort hi = tile[cch * 16 + 2*i + 1][trow];
        q[i] = (uint)lo | ((uint)hi << 16);
    }
    uint4* op = (uint4*)(xT + ((size_t)(b * NN + n0 + trow)) * CC + c0 + cch * 16);
    op[0] = make_uint4(q[0], q[1], q[2], q[3]);
    op[1] = make_uint4(q[4], q[5], q[6], q[7]);
}

// ---------------------------------------------------------------------------
// K1: Gram partials (bf16 MFMA, 4-way K-split, write-once, NO atomics)
//     + row-sum partials for jt==0 blocks
// ---------------------------------------------------------------------------
__global__ __launch_bounds__(256) void gram_mfma(
    const ushort* __restrict__ xbf, float* __restrict__ gpart, float* __restrict__ sPart)
{
    __shared__ ushort As[128][40];
    __shared__ ushort Bs[128][40];
    const int t = threadIdx.x;
    const int jt = blockIdx.x, it = blockIdx.y;
    const int b = blockIdx.z >> 2, kc = blockIdx.z & 3;
    const int iBase = it * 128, jBase = jt * 128;
    const int arow = t >> 1, ah = t & 1;
    const ushort* aSrc = xbf + ((size_t)(b * CC + iBase + arow)) * NN + kc * 512 + ah * 16;
    const ushort* bSrc = xbf + ((size_t)(b * CC + jBase + arow)) * NN + kc * 512 + ah * 16;
    const int lane = t & 63, wid = t >> 6;
    const int mb = (wid >> 1) * 64, nb = (wid & 1) * 64;
    const int lm = lane & 15, q = lane >> 4;
    f32x4 acc[4][4] = {};
    float ssum = 0.f;

    for (int it16 = 0; it16 < 16; ++it16) {
        const uint4* ap = (const uint4*)(aSrc + it16 * 32);
        uint4 a0 = ap[0], a1 = ap[1];
        const uint4* bp = (const uint4*)(bSrc + it16 * 32);
        uint4 b0 = bp[0], b1 = bp[1];
        *(uint4*)&As[arow][ah * 16] = a0;
        *(uint4*)&As[arow][ah * 16 + 8] = a1;
        *(uint4*)&Bs[arow][ah * 16] = b0;
        *(uint4*)&Bs[arow][ah * 16 + 8] = b1;
        if (jt == 0) {
            ssum += bflo(a0.x)+bfhi(a0.x)+bflo(a0.y)+bfhi(a0.y)
                  + bflo(a0.z)+bfhi(a0.z)+bflo(a0.w)+bfhi(a0.w)
                  + bflo(a1.x)+bfhi(a1.x)+bflo(a1.y)+bfhi(a1.y)
                  + bflo(a1.z)+bfhi(a1.z)+bflo(a1.w)+bfhi(a1.w);
        }
        __syncthreads();
        bf16x8 af[4], bf[4];
        #pragma unroll
        for (int mt = 0; mt < 4; ++mt)
            af[mt] = *(const bf16x8*)&As[mb + mt * 16 + lm][q * 8];
        #pragma unroll
        for (int nt = 0; nt < 4; ++nt)
            bf[nt] = *(const bf16x8*)&Bs[nb + nt * 16 + lm][q * 8];
        #pragma unroll
        for (int mt = 0; mt < 4; ++mt)
            #pragma unroll
            for (int nt = 0; nt < 4; ++nt)
                acc[mt][nt] = __builtin_amdgcn_mfma_f32_16x16x32_bf16(af[mt], bf[nt], acc[mt][nt], 0, 0, 0);
        __syncthreads();
    }
    float* gp = gpart + ((size_t)kc * BB + b) * CC * CC;
    #pragma unroll
    for (int mt = 0; mt < 4; ++mt)
        #pragma unroll
        for (int nt = 0; nt < 4; ++nt)
            #pragma unroll
            for (int r = 0; r < 4; ++r) {
                const int gi = iBase + mb + mt * 16 + q * 4 + r;
                const int gj = jBase + nb + nt * 16 + lm;
                gp[(size_t)gi * CC + gj] = acc[mt][nt][r];
            }
    if (jt == 0) {
        const float so = __shfl_xor(ssum, 1);
        if ((t & 1) == 0)
            sPart[((size_t)kc * BB + b) * CC + iBase + arow] = ssum + so;
    }
}

// ---------------------------------------------------------------------------
// K1b: reduce 4 K-split Gram partials
// ---------------------------------------------------------------------------
__global__ __launch_bounds__(256) void gram_reduce(
    const float* __restrict__ gpart, float* __restrict__ Gram)
{
    const int i = blockIdx.x * 256 + threadIdx.x;      // float4 index, 0..262143
    const size_t S = (size_t)BB * CC * CC / 4;
    const float4* p = reinterpret_cast<const float4*>(gpart);
    const float4 a = p[i], b = p[i + S], c = p[i + 2 * S], d = p[i + 3 * S];
    float4 o = { a.x + b.x + c.x + d.x, a.y + b.y + c.y + d.y,
                 a.z + b.z + c.z + d.z, a.w + b.w + c.w + d.w };
    reinterpret_cast<float4*>(Gram)[i] = o;
}

// ---------------------------------------------------------------------------
// K2a: u_b = Gw @ s_b, v_b = Pw @ s_b   (s = sum of 4 K-split partials)
// ---------------------------------------------------------------------------
__global__ __launch_bounds__(256) void uv_kernel(
    const float* __restrict__ Gw, const float* __restrict__ Pw,
    const float* __restrict__ sPart, float* __restrict__ u, float* __restrict__ v)
{
    __shared__ float sLDS[256];
    const int b = blockIdx.x, t = threadIdx.x;
    sLDS[t] = sPart[(size_t)(0 * BB + b) * CC + t]
            + sPart[(size_t)(1 * BB + b) * CC + t]
            + sPart[(size_t)(2 * BB + b) * CC + t]
            + sPart[(size_t)(3 * BB + b) * CC + t];
    __syncthreads();
    const float* wrow = (t < 128) ? (Gw + (size_t)t * CC) : (Pw + (size_t)(t - 128) * CC);
    float acc = 0.f;
    for (int k = 0; k < CC; ++k) acc += wrow[k] * sLDS[k];
    if (t < 128) u[b * II + t] = acc;
    else         v[b * II + (t - 128)] = acc;
}

// ---------------------------------------------------------------------------
// K2b: T1_b = Gw @ Gram_b   [128x256], K=256  (fp32)
// ---------------------------------------------------------------------------
__global__ __launch_bounds__(256) void t1_gemm(
    const float* __restrict__ Gw, const float* __restrict__ Gram, float* __restrict__ T1)
{
    __shared__ float As[32][68];
    __shared__ float Bs[32][64];
    const int tid = threadIdx.x;
    const int jBase = blockIdx.x * 64, iBase = blockIdx.y * 64, b = blockIdx.z;
    const int a_r = tid >> 2, a_k = (tid & 3) * 8;
    const int b_n = tid & 63, b_k = tid >> 6;
    const int ty = tid >> 4, tx = tid & 15;
    float acc[4][4] = {};
    const float* ap0 = Gw + (size_t)(iBase + a_r) * CC + a_k;
    const float* bp0 = Gram + (size_t)b * CC * CC + jBase + b_n;
    for (int k0 = 0; k0 < CC; k0 += 32) {
        #pragma unroll
        for (int j = 0; j < 8; ++j) As[a_k + j][a_r] = ap0[k0 + j];
        #pragma unroll
        for (int kk = 0; kk < 8; ++kk) {
            const int k = b_k + kk * 4;
            Bs[k][b_n] = bp0[(size_t)(k0 + k) * CC];
        }
        __syncthreads();
        #pragma unroll
        for (int k = 0; k < 32; ++k) {
            const float4 av = *(const float4*)&As[k][ty * 4];
            const float4 bv = *(const float4*)&Bs[k][tx * 4];
            MICRO_FMA(av, bv)
        }
        __syncthreads();
    }
    float* dst = T1 + (size_t)b * II * CC;
    #pragma unroll
    for (int ii = 0; ii < 4; ++ii) {
        float4 o = { acc[ii][0], acc[ii][1], acc[ii][2], acc[ii][3] };
        *(float4*)&dst[(size_t)(iBase + ty * 4 + ii) * CC + jBase + tx * 4] = o;
    }
}

// ---------------------------------------------------------------------------
// K2c: K_b = T1_b @ Pw^T + u pb^T + gb v^T + N gb pb^T   [128x128], K=256
// ---------------------------------------------------------------------------
__global__ __launch_bounds__(256) void kb_gemm(
    const float* __restrict__ T1, const float* __restrict__ Pw,
    const float* __restrict__ u, const float* __restrict__ v,
    const float* __restrict__ gb, const float* __restrict__ pb,
    float* __restrict__ Kb)
{
    __shared__ float As[32][68];
    __shared__ float Bs[32][68];
    const int tid = threadIdx.x;
    const int jBase = blockIdx.x * 64, iBase = blockIdx.y * 64, b = blockIdx.z;
    const int a_r = tid >> 2, a_k = (tid & 3) * 8;
    const int ty = tid >> 4, tx = tid & 15;
    float acc[4][4] = {};
    const float* ap0 = T1 + (size_t)b * II * CC + (size_t)(iBase + a_r) * CC + a_k;
    const float* bp0 = Pw + (size_t)(jBase + a_r) * CC + a_k;
    for (int k0 = 0; k0 < CC; k0 += 32) {
        #pragma unroll
        for (int j = 0; j < 8; ++j) As[a_k + j][a_r] = ap0[k0 + j];
        #pragma unroll
        for (int j = 0; j < 8; ++j) Bs[a_k + j][a_r] = bp0[k0 + j];
        __syncthreads();
        #pragma unroll
        for (int k = 0; k < 32; ++k) {
            const float4 av = *(const float4*)&As[k][ty * 4];
            const float4 bv = *(const float4*)&Bs[k][tx * 4];
            MICRO_FMA(av, bv)
        }
        __syncthreads();
    }
    float* dst = Kb + (size_t)b * II * II;
    #pragma unroll
    for (int ii = 0; ii < 4; ++ii) {
        const int gi = iBase + ty * 4 + ii;
        const float ug = u[b * II + gi], gg = gb[gi];
        #pragma unroll
        for (int jj = 0; jj < 4; ++jj) {
            const int gj = jBase + tx * 4 + jj;
            acc[ii][jj] += ug * pb[gj] + gg * (v[b * II + gj] + (float)NN * pb[gj]);
        }
        float4 o = { acc[ii][0], acc[ii][1], acc[ii][2], acc[ii][3] };
        *(float4*)&dst[(size_t)gi * II + jBase + tx * 4] = o;
    }
}

// ---------------------------------------------------------------------------
// K2d: T2_b = Ww @ K_b   [256x128], K=128
// ---------------------------------------------------------------------------
__global__ __launch_bounds__(256) void t2_gemm(
    const float* __restrict__ Ww, const float* __restrict__ Kb, float* __restrict__ T2)
{
    __shared__ float As[32][68];
    __shared__ float Bs[32][64];
    const int tid = threadIdx.x;
    const int jBase = blockIdx.x * 64, iBase = blockIdx.y * 64, b = blockIdx.z;
    const int a_r = tid >> 2, a_k = (tid & 3) * 8;
    const int b_n = tid & 63, b_k = tid >> 6;
    const int ty = tid >> 4, tx = tid & 15;
    float acc[4][4] = {};
    const float* ap0 = Ww + (size_t)(iBase + a_r) * II + a_k;
    const float* bp0 = Kb + (size_t)b * II * II + jBase + b_n;
    for (int k0 = 0; k0 < II; k0 += 32) {
        #pragma unroll
        for (int j = 0; j < 8; ++j) As[a_k + j][a_r] = ap0[k0 + j];
        #pragma unroll
        for (int kk = 0; kk < 8; ++kk) {
            const int k = b_k + kk * 4;
            Bs[k][b_n] = bp0[(size_t)(k0 + k) * II];
        }
        __syncthreads();
        #pragma unroll
        for (int k = 0; k < 32; ++k) {
            const float4 av = *(const float4*)&As[k][ty * 4];
            const float4 bv = *(const float4*)&Bs[k][tx * 4];
            MICRO_FMA(av, bv)
        }
        __syncthreads();
    }
    float* dst = T2 + (size_t)b * CC * II;
    #pragma unroll
    for (int ii = 0; ii < 4; ++ii) {
        float4 o = { acc[ii][0], acc[ii][1], acc[ii][2], acc[ii][3] };
        *(float4*)&dst[(size_t)(iBase + ty * 4 + ii) * II + jBase + tx * 4] = o;
    }
}

// ---------------------------------------------------------------------------
// K2f: S_b = T2_b @ Tw / N -> bf16;  c'_b = T2_b @ tb / N (shfl, no atomics)
// ---------------------------------------------------------------------------
__global__ __launch_bounds__(256) void s_gemm(
    const float* __restrict__ T2, const float* __restrict__ Tw,
    const float* __restrict__ tb, float* __restrict__ cprime,
    ushort* __restrict__ Sbf)
{
    __shared__ float As[32][68];
    __shared__ float Bs[32][64];
    const int tid = threadIdx.x;
    const int jBase = blockIdx.x * 64, iBase = blockIdx.y * 64, b = blockIdx.z;
    const int a_r = tid >> 2, a_k = (tid & 3) * 8;
    const int b_n = tid & 63, b_k = tid >> 6;
    const int ty = tid >> 4, tx = tid & 15;
    float acc[4][4] = {};
    float cp = 0.f;
    const float* ap0 = T2 + (size_t)b * CC * II + (size_t)(iBase + a_r) * II + a_k;
    const float* bp0 = Tw + jBase + b_n;
    for (int k0 = 0; k0 < II; k0 += 32) {
        #pragma unroll
        for (int j = 0; j < 8; ++j) {
            const float v = ap0[k0 + j];
            As[a_k + j][a_r] = v;
            if (blockIdx.x == 0) cp += v * tb[k0 + a_k + j];
        }
        #pragma unroll
        for (int kk = 0; kk < 8; ++kk) {
            const int k = b_k + kk * 4;
            Bs[k][b_n] = bp0[(size_t)(k0 + k) * CC];
        }
        __syncthreads();
        #pragma unroll
        for (int k = 0; k < 32; ++k) {
            const float4 av = *(const float4*)&As[k][ty * 4];
            const float4 bv = *(const float4*)&Bs[k][tx * 4];
            MICRO_FMA(av, bv)
        }
        __syncthreads();
    }
    const float sc = 1.0f / (float)NN;
    if (blockIdx.x == 0) {
        float c2 = cp + __shfl_xor(cp, 1);
        c2 += __shfl_xor(c2, 2);
        if ((tid & 3) == 0) cprime[b * CC + iBase + a_r] = c2 * sc;
    }
    ushort* dst = Sbf + (size_t)b * CC * CC;
    #pragma unroll
    for (int ii = 0; ii < 4; ++ii) {
        const int gi = iBase + ty * 4 + ii;
        uint p0 = (uint)f2bf(acc[ii][0] * sc) | ((uint)f2bf(acc[ii][1] * sc) << 16);
        uint p1 = (uint)f2bf(acc[ii][2] * sc) | ((uint)f2bf(acc[ii][3] * sc) << 16);
        uint2 o = { p0, p1 };
        *(uint2*)&dst[(size_t)gi * CC + jBase + tx * 4] = o;
    }
}

// ---------------------------------------------------------------------------
// K3: z_b = S_b @ x_b + c' 1^T (bf16 MFMA) -> zbf; per-block BN partials (no atomics)
// ---------------------------------------------------------------------------
__global__ __launch_bounds__(256) void z_mfma(
    const ushort* __restrict__ Sbf, const ushort* __restrict__ xT,
    const float* __restrict__ cprime, ushort* __restrict__ zbf,
    float* __restrict__ statsPart)
{
    __shared__ ushort As[128][40];
    __shared__ ushort Bs[128][40];
    __shared__ float cpL[128];
    __shared__ float sSum[2][128], sSq[2][128];
    const int t = threadIdx.x;
    const int n0 = blockIdx.x * 128, ct = blockIdx.y * 128, b = blockIdx.z;
    const int arow = t >> 1, ah = t & 1;
    const ushort* aSrc = Sbf + ((size_t)(b * CC + ct + arow)) * CC + ah * 16;
    const ushort* bSrc = xT + ((size_t)(b * NN + n0 + arow)) * CC + ah * 16;
    const int lane = t & 63, wid = t >> 6;
    const int mb = (wid >> 1) * 64, nb = (wid & 1) * 64;
    const int lm = lane & 15, q = lane >> 4;
    f32x4 acc[4][4] = {};

    if (t < 128) cpL[t] = cprime[b * CC + ct + t];

    for (int k0 = 0; k0 < CC; k0 += 32) {
        const uint4* ap = (const uint4*)(aSrc + k0);
        uint4 a0 = ap[0], a1 = ap[1];
        const uint4* bp = (const uint4*)(bSrc + k0);
        uint4 b0 = bp[0], b1 = bp[1];
        *(uint4*)&As[arow][ah * 16] = a0;
        *(uint4*)&As[arow][ah * 16 + 8] = a1;
        *(uint4*)&Bs[arow][ah * 16] = b0;
        *(uint4*)&Bs[arow][ah * 16 + 8] = b1;
        __syncthreads();
        bf16x8 af[4], bf[4];
        #pragma unroll
        for (int mt = 0; mt < 4; ++mt)
            af[mt] = *(const bf16x8*)&As[mb + mt * 16 + lm][q * 8];
        #pragma unroll
        for (int nt = 0; nt < 4; ++nt)
            bf[nt] = *(const bf16x8*)&Bs[nb + nt * 16 + lm][q * 8];
        #pragma unroll
        for (int mt = 0; mt < 4; ++mt)
            #pragma unroll
            for (int nt = 0; nt < 4; ++nt)
                acc[mt][nt] = __builtin_amdgcn_mfma_f32_16x16x32_bf16(af[mt], bf[nt], acc[mt][nt], 0, 0, 0);
        __syncthreads();
    }
    const int nbw = wid & 1;
    #pragma unroll
    for (int mt = 0; mt < 4; ++mt) {
        #pragma unroll
        for (int r = 0; r < 4; ++r) {
            const int cl = mb + mt * 16 + q * 4 + r;
            const int ci = ct + cl;
            const float cp = cpL[cl];
            const size_t zrow = ((size_t)(b * CC + ci)) * NN;
            float s1 = 0.f, q1 = 0.f;
            #pragma unroll
            for (int nt = 0; nt < 4; ++nt) {
                const float val = acc[mt][nt][r] + cp;
                const int tok = n0 + nb + nt * 16 + lm;
                zbf[zrow + tok] = f2bf(val);
                s1 += val; q1 += val * val;
            }
            #pragma unroll
            for (int m = 1; m < 16; m <<= 1) {
                s1 += __shfl_xor(s1, m);
                q1 += __shfl_xor(q1, m);
            }
            if (lm == 0) { sSum[nbw][cl] = s1; sSq[nbw][cl] = q1; }
        }
    }
    __syncthreads();
    if (t < 128) {
        const int slot = blockIdx.z * 16 + blockIdx.x;
        statsPart[(size_t)slot * 512 + ct + t]       = sSum[0][t] + sSum[1][t];
        statsPart[(size_t)slot * 512 + 256 + ct + t] = sSq[0][t] + sSq[1][t];
    }
}

// ---------------------------------------------------------------------------
// K4: finalize stats (reduce 256 slot partials per channel)
// ---------------------------------------------------------------------------
__global__ __launch_bounds__(512) void bn_finalize(
    const float* __restrict__ statsPart, float* __restrict__ stats2)
{
    __shared__ float red[512];
    const int t = threadIdx.x;           // t<256: sum for channel t; t>=256: sumsq
    float a = 0.f;
    for (int s = 0; s < 256; ++s) a += statsPart[(size_t)s * 512 + t];
    red[t] = a;
    __syncthreads();
    if (t < 256) {
        const float cnt = (float)(BB * NN);
        const float mean = red[t] / cnt;
        const float var = red[256 + t] / cnt - mean * mean;
        stats2[t] = mean;
        stats2[CC + t] = rsqrtf(var + BN_EPS);
    }
}

// ---------------------------------------------------------------------------
// K5: out = (z - mean)*istd*gamma + beta + x
// ---------------------------------------------------------------------------
__global__ __launch_bounds__(256) void bn_apply(
    const ushort* __restrict__ zbf, const float* __restrict__ x,
    float* __restrict__ out, const float* __restrict__ stats2,
    const float* __restrict__ gamma, const float* __restrict__ beta)
{
    const size_t i = (size_t)blockIdx.x * 256 + threadIdx.x;
    const size_t base = i * 8;
    const int c = (int)((base >> 11) & (CC - 1));
    const float mean = stats2[c], istd = stats2[CC + c];
    const float gm = gamma[c] * istd;
    const float bt = beta[c] - mean * gm;
    const uint4 zz = *(const uint4*)(zbf + base);
    const float4 x0 = *(const float4*)(x + base);
    const float4 x1 = *(const float4*)(x + base + 4);
    float4 o0, o1;
    o0.x = bflo(zz.x) * gm + bt + x0.x;  o0.y = bfhi(zz.x) * gm + bt + x0.y;
    o0.z = bflo(zz.y) * gm + bt + x0.z;  o0.w = bfhi(zz.y) * gm + bt + x0.w;
    o1.x = bflo(zz.z) * gm + bt + x1.x;  o1.y = bfhi(zz.z) * gm + bt + x1.y;
    o1.z = bflo(zz.w) * gm + bt + x1.z;  o1.w = bfhi(zz.w) * gm + bt + x1.w;
    *(float4*)(out + base) = o0;
    *(float4*)(out + base + 4) = o1;
}

// ---------------------------------------------------------------------------
extern "C" void kernel_launch(void* const* d_in, const int* in_sizes, int n_in,
                              void* d_out, int out_size, void* d_ws, size_t ws_size,
                              hipStream_t stream) {
    const float* x    = (const float*)d_in[0];
    const float* g_w  = (const float*)d_in[1];
    const float* g_b  = (const float*)d_in[2];
    const float* th_w = (const float*)d_in[3];
    const float* th_b = (const float*)d_in[4];
    const float* ph_w = (const float*)d_in[5];
    const float* ph_b = (const float*)d_in[6];
    const float* W_w  = (const float*)d_in[7];
    // d_in[8] (W_b) cancels exactly in batch-norm
    const float* bn_g = (const float*)d_in[9];
    const float* bn_bt= (const float*)d_in[10];
    float* wsf = (float*)d_ws;
    float* out = (float*)d_out;

    ushort* SBF = (ushort*)(wsf + OFF_FEND);
    ushort* XBF = SBF + USZ_SBF;
    ushort* XT  = XBF + USZ_X;
    ushort* ZBF = XT + USZ_X;

    convert_transpose<<<dim3(32, 4, 16), 256, 0, stream>>>(x, XBF, XT);
    gram_mfma<<<dim3(2, 2, 64), 256, 0, stream>>>(XBF, wsf + OFF_GPART, wsf + OFF_SPART);
    gram_reduce<<<dim3(1024), 256, 0, stream>>>(wsf + OFF_GPART, wsf + OFF_GRAM);
    uv_kernel<<<dim3(16), 256, 0, stream>>>(g_w, ph_w, wsf + OFF_SPART, wsf + OFF_U, wsf + OFF_V);
    t1_gemm<<<dim3(4, 2, 16), 256, 0, stream>>>(g_w, wsf + OFF_GRAM, wsf + OFF_T1);
    kb_gemm<<<dim3(2, 2, 16), 256, 0, stream>>>(wsf + OFF_T1, ph_w, wsf + OFF_U, wsf + OFF_V,
                                                g_b, ph_b, wsf + OFF_KB);
    t2_gemm<<<dim3(2, 4, 16), 256, 0, stream>>>(W_w, wsf + OFF_KB, wsf + OFF_T2);
    s_gemm<<<dim3(4, 4, 16), 256, 0, stream>>>(wsf + OFF_T2, th_w, th_b, wsf + OFF_CP, SBF);
    z_mfma<<<dim3(16, 2, 16), 256, 0, stream>>>(SBF, XT, wsf + OFF_CP, ZBF, wsf + OFF_STATP);
    bn_finalize<<<dim3(1), 512, 0, stream>>>(wsf + OFF_STATP, wsf + OFF_STAT2);
    bn_apply<<<dim3(4096), 256, 0, stream>>>(ZBF, x, out, wsf + OFF_STAT2, bn_g, bn_bt);
}

// Round 4
// 225.260 us; speedup vs baseline: 1.3319x; 1.0204x over previous
//
#include <hip/hip_runtime.h>

typedef unsigned int uint;
typedef unsigned short ushort;
typedef __attribute__((ext_vector_type(8))) short bf16x8;
typedef __attribute__((ext_vector_type(4))) float f32x4;

#define BB 16
#define CC 256
#define II 128
#define NN 2048
#define BN_EPS 1e-5f

// ---- float workspace offsets (all write-once, no zero-init) ----
#define OFF_GPART 0            // [4][16][256][256] = 4,194,304
#define OFF_SPART 4194304      // [4][16][256]      = 16,384
#define OFF_CP    4210688      // [16][256]         = 4,096
#define OFF_STATP 4214784      // [256][512]        = 131,072
#define OFF_STAT2 4345856      // [512]
#define OFF_PT    4346368      // [256]
#define OFF_R1    4346624      // [256]
#define OFF_WGB   4346880      // [256]
#define OFF_ALPHA 4347136      // [16]
#define OFF_L1    4347152      // [16][256] = 4096
#define OFF_R2    4351248      // [16][256] = 4096
#define OFF_FEND  4355344
// ---- ushort offsets relative to (ushort*)(wsf + OFF_FEND) ----
#define UGRAM 0                // [16][256][256] bf16
#define UE    1048576          // [256][256]
#define UFT   1114112          // [256][256]  (= (Pw^T Tw)^T / N)
#define UHT   1179648          // [16][256][256]
#define USBF  2228224          // [16][256][256]
#define UXT   3276800          // [16][2048][256]
#define UZ    11665408         // [16][256][2048]

static __device__ __forceinline__ ushort f2bf(float f) {
    uint u = __float_as_uint(f);
    return (ushort)((u + 0x7FFFu + ((u >> 16) & 1u)) >> 16);
}
static __device__ __forceinline__ uint pack2(float a, float b) {
    return (uint)f2bf(a) | ((uint)f2bf(b) << 16);
}
static __device__ __forceinline__ float bflo(uint w) { return __uint_as_float(w << 16); }
static __device__ __forceinline__ float bfhi(uint w) { return __uint_as_float(w & 0xFFFF0000u); }
static __device__ __forceinline__ float bfu(ushort u) { return __uint_as_float((uint)u << 16); }

#define MICRO_FMA(av, bv) \
    acc[0][0] += av.x * bv.x; acc[0][1] += av.x * bv.y; acc[0][2] += av.x * bv.z; acc[0][3] += av.x * bv.w; \
    acc[1][0] += av.y * bv.x; acc[1][1] += av.y * bv.y; acc[1][2] += av.y * bv.z; acc[1][3] += av.y * bv.w; \
    acc[2][0] += av.z * bv.x; acc[2][1] += av.z * bv.y; acc[2][2] += av.z * bv.z; acc[2][3] += av.z * bv.w; \
    acc[3][0] += av.w * bv.x; acc[3][1] += av.w * bv.y; acc[3][2] += av.w * bv.z; acc[3][3] += av.w * bv.w;

// ---------------------------------------------------------------------------
// K0: x (fp32 [b][c][n]) -> xT (bf16 [b][n][c])   (XBF dropped)
// ---------------------------------------------------------------------------
__global__ __launch_bounds__(256) void convert_xt(
    const float* __restrict__ x, ushort* __restrict__ xT)
{
    __shared__ ushort tile[64][72];
    const int t = threadIdx.x;
    const int b = blockIdx.z, c0 = blockIdx.y * 64, n0 = blockIdx.x * 64;
    const int row = t & 63, ch = t >> 6;
    const size_t srcIdx = ((size_t)(b * CC + c0 + row)) * NN + n0 + ch * 16;
    const float4* sp = (const float4*)(x + srcIdx);
    float4 v0 = sp[0], v1 = sp[1], v2 = sp[2], v3 = sp[3];
    uint p[8];
    p[0] = pack2(v0.x, v0.y); p[1] = pack2(v0.z, v0.w);
    p[2] = pack2(v1.x, v1.y); p[3] = pack2(v1.z, v1.w);
    p[4] = pack2(v2.x, v2.y); p[5] = pack2(v2.z, v2.w);
    p[6] = pack2(v3.x, v3.y); p[7] = pack2(v3.z, v3.w);
    uint* tp = (uint*)&tile[row][ch * 16];
    #pragma unroll
    for (int i = 0; i < 8; ++i) tp[i] = p[i];
    __syncthreads();
    const int trow = t & 63, cch = t >> 6;
    uint q[8];
    #pragma unroll
    for (int i = 0; i < 8; ++i) {
        ushort lo = tile[cch * 16 + 2*i][trow];
        ushort hi = tile[cch * 16 + 2*i + 1][trow];
        q[i] = (uint)lo | ((uint)hi << 16);
    }
    uint4* op = (uint4*)(xT + ((size_t)(b * NN + n0 + trow)) * CC + c0 + cch * 16);
    op[0] = make_uint4(q[0], q[1], q[2], q[3]);
    op[1] = make_uint4(q[4], q[5], q[6], q[7]);
}

// ---------------------------------------------------------------------------
// K1: Gram partials from fp32 x (on-the-fly bf16), 4-way K-split, no atomics
// ---------------------------------------------------------------------------
__global__ __launch_bounds__(256) void gram_mfma(
    const float* __restrict__ x, float* __restrict__ gpart, float* __restrict__ sPart)
{
    __shared__ ushort As[128][40];
    __shared__ ushort Bs[128][40];
    const int t = threadIdx.x;
    const int jt = blockIdx.x, it = blockIdx.y;
    const int b = blockIdx.z >> 2, kc = blockIdx.z & 3;
    const int iBase = it * 128, jBase = jt * 128;
    const int arow = t >> 1, ah = t & 1;
    const float* aSrc = x + ((size_t)(b * CC + iBase + arow)) * NN + kc * 512 + ah * 16;
    const float* bSrc = x + ((size_t)(b * CC + jBase + arow)) * NN + kc * 512 + ah * 16;
    const int lane = t & 63, wid = t >> 6;
    const int mb = (wid >> 1) * 64, nb = (wid & 1) * 64;
    const int lm = lane & 15, q = lane >> 4;
    f32x4 acc[4][4] = {};
    float ssum = 0.f;

    for (int it16 = 0; it16 < 16; ++it16) {
        const float4* ap = (const float4*)(aSrc + it16 * 32);
        float4 a0 = ap[0], a1 = ap[1], a2 = ap[2], a3 = ap[3];
        const float4* bp = (const float4*)(bSrc + it16 * 32);
        float4 b0 = bp[0], b1 = bp[1], b2 = bp[2], b3 = bp[3];
        uint4 pa0 = { pack2(a0.x,a0.y), pack2(a0.z,a0.w), pack2(a1.x,a1.y), pack2(a1.z,a1.w) };
        uint4 pa1 = { pack2(a2.x,a2.y), pack2(a2.z,a2.w), pack2(a3.x,a3.y), pack2(a3.z,a3.w) };
        uint4 pb0 = { pack2(b0.x,b0.y), pack2(b0.z,b0.w), pack2(b1.x,b1.y), pack2(b1.z,b1.w) };
        uint4 pb1 = { pack2(b2.x,b2.y), pack2(b2.z,b2.w), pack2(b3.x,b3.y), pack2(b3.z,b3.w) };
        *(uint4*)&As[arow][ah * 16]     = pa0;
        *(uint4*)&As[arow][ah * 16 + 8] = pa1;
        *(uint4*)&Bs[arow][ah * 16]     = pb0;
        *(uint4*)&Bs[arow][ah * 16 + 8] = pb1;
        if (jt == 0) {
            ssum += a0.x+a0.y+a0.z+a0.w + a1.x+a1.y+a1.z+a1.w
                  + a2.x+a2.y+a2.z+a2.w + a3.x+a3.y+a3.z+a3.w;
        }
        __syncthreads();
        bf16x8 af[4], bf[4];
        #pragma unroll
        for (int mt = 0; mt < 4; ++mt)
            af[mt] = *(const bf16x8*)&As[mb + mt * 16 + lm][q * 8];
        #pragma unroll
        for (int nt = 0; nt < 4; ++nt)
            bf[nt] = *(const bf16x8*)&Bs[nb + nt * 16 + lm][q * 8];
        #pragma unroll
        for (int mt = 0; mt < 4; ++mt)
            #pragma unroll
            for (int nt = 0; nt < 4; ++nt)
                acc[mt][nt] = __builtin_amdgcn_mfma_f32_16x16x32_bf16(af[mt], bf[nt], acc[mt][nt], 0, 0, 0);
        __syncthreads();
    }
    float* gp = gpart + ((size_t)kc * BB + b) * CC * CC;
    #pragma unroll
    for (int mt = 0; mt < 4; ++mt)
        #pragma unroll
        for (int nt = 0; nt < 4; ++nt)
            #pragma unroll
            for (int r = 0; r < 4; ++r) {
                const int gi = iBase + mb + mt * 16 + q * 4 + r;
                const int gj = jBase + nb + nt * 16 + lm;
                gp[(size_t)gi * CC + gj] = acc[mt][nt][r];
            }
    if (jt == 0) {
        const float so = __shfl_xor(ssum, 1);
        if ((t & 1) == 0)
            sPart[((size_t)kc * BB + b) * CC + iBase + arow] = ssum + so;
    }
}

// ---------------------------------------------------------------------------
// K1b: reduce 4 Gram partials -> GramBF (bf16)
// ---------------------------------------------------------------------------
__global__ __launch_bounds__(256) void gram_reduce(
    const float* __restrict__ gpart, ushort* __restrict__ GramBF)
{
    const int i = blockIdx.x * 256 + threadIdx.x;      // float4 idx, 0..262143
    const size_t S = (size_t)BB * CC * CC / 4;
    const float4* p = (const float4*)gpart;
    const float4 a = p[i], b = p[i + S], c = p[i + 2 * S], d = p[i + 3 * S];
    float4 o = { a.x + b.x + c.x + d.x, a.y + b.y + c.y + d.y,
                 a.z + b.z + c.z + d.z, a.w + b.w + c.w + d.w };
    uint2 pk = { pack2(o.x, o.y), pack2(o.z, o.w) };
    ((uint2*)GramBF)[i] = pk;
}

// ---------------------------------------------------------------------------
// K2: weight precompute. bz<16: E = Ww@Gw tile; bz<32: FT = (Pw^T Tw)^T/N tile;
//     bz==32: vectors pt = Pw^T tb, r1 = Tw^T pb, wgb = Ww gb, alpha = pb.tb
// ---------------------------------------------------------------------------
__global__ __launch_bounds__(256) void w1_kernel(
    const float* __restrict__ Ww, const float* __restrict__ Gw,
    const float* __restrict__ Pw, const float* __restrict__ Tw,
    const float* __restrict__ gb, const float* __restrict__ pb, const float* __restrict__ tb,
    ushort* __restrict__ EBF, ushort* __restrict__ FT,
    float* __restrict__ pt, float* __restrict__ r1, float* __restrict__ wgb,
    float* __restrict__ alpha)
{
    const int bz = blockIdx.x;
    const int tid = threadIdx.x;
    if (bz == 32) {
        const int t = tid;
        float ptv = 0.f, r1v = 0.f, wgbv = 0.f;
        for (int d = 0; d < II; ++d) {
            ptv  += Pw[(size_t)d * CC + t] * tb[d];
            r1v  += Tw[(size_t)d * CC + t] * pb[d];
            wgbv += Ww[(size_t)t * II + d] * gb[d];
        }
        pt[t] = ptv; r1[t] = r1v; wgb[t] = wgbv;
        if (t == 0) {
            float al = 0.f;
            for (int d = 0; d < II; ++d) al += pb[d] * tb[d];
            alpha[0] = al;
        }
        return;
    }
    __shared__ float As[32][68];
    __shared__ float Bs[32][68];
    const int a_r = tid >> 2, a_k = (tid & 3) * 8;
    const int b_n = tid & 63, b_k = tid >> 6;
    const int ty = tid >> 4, tx = tid & 15;
    float acc[4][4] = {};
    if (bz < 16) {
        // E[c][i] = sum_e Ww[c][e]*Gw[e][i]
        const int cBase = (bz >> 2) * 64, iBase = (bz & 3) * 64;
        const float* ap0 = Ww + (size_t)(cBase + a_r) * II + a_k;
        const float* bp0 = Gw + iBase + b_n;
        for (int k0 = 0; k0 < II; k0 += 32) {
            #pragma unroll
            for (int j = 0; j < 8; ++j) As[a_k + j][a_r] = ap0[k0 + j];
            #pragma unroll
            for (int kk = 0; kk < 8; ++kk) {
                const int k = b_k + kk * 4;
                Bs[k][b_n] = bp0[(size_t)(k0 + k) * CC];
            }
            __syncthreads();
            #pragma unroll
            for (int k = 0; k < 32; ++k) {
                const float4 av = *(const float4*)&As[k][ty * 4];
                const float4 bv = *(const float4*)&Bs[k][tx * 4];
                MICRO_FMA(av, bv)
            }
            __syncthreads();
        }
        #pragma unroll
        for (int ii = 0; ii < 4; ++ii) {
            uint2 o = { pack2(acc[ii][0], acc[ii][1]), pack2(acc[ii][2], acc[ii][3]) };
            *(uint2*)&EBF[(size_t)(cBase + ty * 4 + ii) * CC + iBase + tx * 4] = o;
        }
    } else {
        // FT[j][k] = (1/N) * sum_d Tw[d][j]*Pw[d][k]
        const int z = bz - 16;
        const int jBase = (z >> 2) * 64, kBase = (z & 3) * 64;
        const float* ap0 = Tw + jBase + b_n;
        const float* bp0 = Pw + kBase + b_n;
        for (int k0 = 0; k0 < II; k0 += 32) {
            #pragma unroll
            for (int kk = 0; kk < 8; ++kk) {
                const int k = b_k + kk * 4;
                As[k][b_n] = ap0[(size_t)(k0 + k) * CC];
                Bs[k][b_n] = bp0[(size_t)(k0 + k) * CC];
            }
            __syncthreads();
            #pragma unroll
            for (int k = 0; k < 32; ++k) {
                const float4 av = *(const float4*)&As[k][ty * 4];
                const float4 bv = *(const float4*)&Bs[k][tx * 4];
                MICRO_FMA(av, bv)
            }
            __syncthreads();
        }
        const float sc = 1.0f / (float)NN;
        #pragma unroll
        for (int ii = 0; ii < 4; ++ii) {
            uint2 o = { pack2(acc[ii][0]*sc, acc[ii][1]*sc), pack2(acc[ii][2]*sc, acc[ii][3]*sc) };
            *(uint2*)&FT[(size_t)(jBase + ty * 4 + ii) * CC + kBase + tx * 4] = o;
        }
    }
}

// ---------------------------------------------------------------------------
// K3: per-batch vectors: s_b, then L1 = E s/N, R2 = FT s + r1,
//     cprime = (E(Gram pt) + a*Es + (s.pt)*wgb)/N + a*wgb
// ---------------------------------------------------------------------------
__global__ __launch_bounds__(256) void u_kernel(
    const float* __restrict__ sPart, const ushort* __restrict__ GramBF,
    const ushort* __restrict__ EBF, const ushort* __restrict__ FT,
    const float* __restrict__ pt, const float* __restrict__ r1,
    const float* __restrict__ wgb, const float* __restrict__ alpha,
    float* __restrict__ cprime, float* __restrict__ L1, float* __restrict__ R2)
{
    __shared__ float sL[256], ptL[256], GptL[256], red[256];
    const int b = blockIdx.x, t = threadIdx.x;
    sL[t] = sPart[(size_t)(0 * BB + b) * CC + t] + sPart[(size_t)(1 * BB + b) * CC + t]
          + sPart[(size_t)(2 * BB + b) * CC + t] + sPart[(size_t)(3 * BB + b) * CC + t];
    ptL[t] = pt[t];
    __syncthreads();
    red[t] = sL[t] * ptL[t];
    __syncthreads();
    for (int s = 128; s > 0; s >>= 1) {
        if (t < s) red[t] += red[t + s];
        __syncthreads();
    }
    const float spt = red[0];
    // Gpt[i=t] = sum_k Gram[i][k]*pt[k]
    {
        const uint4* gp = (const uint4*)(GramBF + ((size_t)b * CC + t) * CC);
        float g = 0.f;
        #pragma unroll 4
        for (int kk = 0; kk < 32; ++kk) {
            uint4 v = gp[kk]; const int k = kk * 8;
            g += bflo(v.x)*ptL[k]   + bfhi(v.x)*ptL[k+1] + bflo(v.y)*ptL[k+2] + bfhi(v.y)*ptL[k+3]
               + bflo(v.z)*ptL[k+4] + bfhi(v.z)*ptL[k+5] + bflo(v.w)*ptL[k+6] + bfhi(v.w)*ptL[k+7];
        }
        GptL[t] = g;
    }
    __syncthreads();
    float es = 0.f, eg = 0.f;
    {
        const uint4* ep = (const uint4*)(EBF + (size_t)t * CC);
        #pragma unroll 4
        for (int kk = 0; kk < 32; ++kk) {
            uint4 v = ep[kk]; const int k = kk * 8;
            float e0=bflo(v.x),e1=bfhi(v.x),e2=bflo(v.y),e3=bfhi(v.y);
            float e4=bflo(v.z),e5=bfhi(v.z),e6=bflo(v.w),e7=bfhi(v.w);
            es += e0*sL[k]+e1*sL[k+1]+e2*sL[k+2]+e3*sL[k+3]+e4*sL[k+4]+e5*sL[k+5]+e6*sL[k+6]+e7*sL[k+7];
            eg += e0*GptL[k]+e1*GptL[k+1]+e2*GptL[k+2]+e3*GptL[k+3]+e4*GptL[k+4]+e5*GptL[k+5]+e6*GptL[k+6]+e7*GptL[k+7];
        }
    }
    float r2 = 0.f;
    {
        const uint4* fp = (const uint4*)(FT + (size_t)t * CC);
        #pragma unroll 4
        for (int kk = 0; kk < 32; ++kk) {
            uint4 v = fp[kk]; const int k = kk * 8;
            r2 += bflo(v.x)*sL[k]   + bfhi(v.x)*sL[k+1] + bflo(v.y)*sL[k+2] + bfhi(v.y)*sL[k+3]
                + bflo(v.z)*sL[k+4] + bfhi(v.z)*sL[k+5] + bflo(v.w)*sL[k+6] + bfhi(v.w)*sL[k+7];
        }
    }
    const float al = alpha[0];
    const float wg = wgb[t];
    cprime[b * CC + t] = (eg + al * es + spt * wg) / (float)NN + al * wg;
    L1[b * CC + t] = es / (float)NN;
    R2[b * CC + t] = r2 + r1[t];
}

// ---------------------------------------------------------------------------
// K4: HT_b[j][i] = sum_k FsT[j][k] * Gram_b[i][k]   (Gram symmetric; bf16 MFMA)
// ---------------------------------------------------------------------------
__global__ __launch_bounds__(256) void h_mfma(
    const ushort* __restrict__ FT, const ushort* __restrict__ GramBF,
    ushort* __restrict__ HT)
{
    __shared__ ushort As[128][40];
    __shared__ ushort Bs[128][40];
    const int t = threadIdx.x;
    const int iBase = blockIdx.x * 128, jBase = blockIdx.y * 128, b = blockIdx.z;
    const int arow = t >> 1, ah = t & 1;
    const ushort* aSrc = FT + (size_t)(jBase + arow) * CC + ah * 16;
    const ushort* bSrc = GramBF + ((size_t)b * CC + iBase + arow) * CC + ah * 16;
    const int lane = t & 63, wid = t >> 6;
    const int mb = (wid >> 1) * 64, nb = (wid & 1) * 64;
    const int lm = lane & 15, q = lane >> 4;
    f32x4 acc[4][4] = {};
    for (int k0 = 0; k0 < CC; k0 += 32) {
        *(uint4*)&As[arow][ah * 16]     = ((const uint4*)(aSrc + k0))[0];
        *(uint4*)&As[arow][ah * 16 + 8] = ((const uint4*)(aSrc + k0))[1];
        *(uint4*)&Bs[arow][ah * 16]     = ((const uint4*)(bSrc + k0))[0];
        *(uint4*)&Bs[arow][ah * 16 + 8] = ((const uint4*)(bSrc + k0))[1];
        __syncthreads();
        bf16x8 af[4], bf[4];
        #pragma unroll
        for (int mt = 0; mt < 4; ++mt)
            af[mt] = *(const bf16x8*)&As[mb + mt * 16 + lm][q * 8];
        #pragma unroll
        for (int nt = 0; nt < 4; ++nt)
            bf[nt] = *(const bf16x8*)&Bs[nb + nt * 16 + lm][q * 8];
        #pragma unroll
        for (int mt = 0; mt < 4; ++mt)
            #pragma unroll
            for (int nt = 0; nt < 4; ++nt)
                acc[mt][nt] = __builtin_amdgcn_mfma_f32_16x16x32_bf16(af[mt], bf[nt], acc[mt][nt], 0, 0, 0);
        __syncthreads();
    }
    ushort* dst = HT + (size_t)b * CC * CC;
    #pragma unroll
    for (int mt = 0; mt < 4; ++mt)
        #pragma unroll
        for (int r = 0; r < 4; ++r) {
            const int j = jBase + mb + mt * 16 + q * 4 + r;
            #pragma unroll
            for (int nt = 0; nt < 4; ++nt) {
                const int i = iBase + nb + nt * 16 + lm;
                dst[(size_t)j * CC + i] = f2bf(acc[mt][nt][r]);
            }
        }
}

// ---------------------------------------------------------------------------
// K5: S_b[c][j] = sum_i E[c][i]*HT_b[j][i] + L1[c]*r1[j] + wgb[c]*R2[j] -> bf16
// ---------------------------------------------------------------------------
__global__ __launch_bounds__(256) void s2_mfma(
    const ushort* __restrict__ EBF, const ushort* __restrict__ HT,
    const float* __restrict__ r1, const float* __restrict__ R2,
    const float* __restrict__ L1, const float* __restrict__ wgb,
    ushort* __restrict__ Sbf)
{
    __shared__ ushort As[128][40];
    __shared__ ushort Bs[128][40];
    const int t = threadIdx.x;
    const int jBase = blockIdx.x * 128, cBase = blockIdx.y * 128, b = blockIdx.z;
    const int arow = t >> 1, ah = t & 1;
    const ushort* aSrc = EBF + (size_t)(cBase + arow) * CC + ah * 16;
    const ushort* bSrc = HT + ((size_t)b * CC + jBase + arow) * CC + ah * 16;
    const int lane = t & 63, wid = t >> 6;
    const int mb = (wid >> 1) * 64, nb = (wid & 1) * 64;
    const int lm = lane & 15, q = lane >> 4;
    f32x4 acc[4][4] = {};
    for (int k0 = 0; k0 < CC; k0 += 32) {
        *(uint4*)&As[arow][ah * 16]     = ((const uint4*)(aSrc + k0))[0];
        *(uint4*)&As[arow][ah * 16 + 8] = ((const uint4*)(aSrc + k0))[1];
        *(uint4*)&Bs[arow][ah * 16]     = ((const uint4*)(bSrc + k0))[0];
        *(uint4*)&Bs[arow][ah * 16 + 8] = ((const uint4*)(bSrc + k0))[1];
        __syncthreads();
        bf16x8 af[4], bf[4];
        #pragma unroll
        for (int mt = 0; mt < 4; ++mt)
            af[mt] = *(const bf16x8*)&As[mb + mt * 16 + lm][q * 8];
        #pragma unroll
        for (int nt = 0; nt < 4; ++nt)
            bf[nt] = *(const bf16x8*)&Bs[nb + nt * 16 + lm][q * 8];
        #pragma unroll
        for (int mt = 0; mt < 4; ++mt)
            #pragma unroll
            for (int nt = 0; nt < 4; ++nt)
                acc[mt][nt] = __builtin_amdgcn_mfma_f32_16x16x32_bf16(af[mt], bf[nt], acc[mt][nt], 0, 0, 0);
        __syncthreads();
    }
    float r1v[4], R2v[4];
    #pragma unroll
    for (int nt = 0; nt < 4; ++nt) {
        const int j = jBase + nb + nt * 16 + lm;
        r1v[nt] = r1[j];
        R2v[nt] = R2[b * CC + j];
    }
    ushort* dst = Sbf + (size_t)b * CC * CC;
    #pragma unroll
    for (int mt = 0; mt < 4; ++mt)
        #pragma unroll
        for (int r = 0; r < 4; ++r) {
            const int c = cBase + mb + mt * 16 + q * 4 + r;
            const float l1v = L1[b * CC + c], wgv = wgb[c];
            #pragma unroll
            for (int nt = 0; nt < 4; ++nt) {
                const int j = jBase + nb + nt * 16 + lm;
                dst[(size_t)c * CC + j] = f2bf(acc[mt][nt][r] + l1v * r1v[nt] + wgv * R2v[nt]);
            }
        }
}

// ---------------------------------------------------------------------------
// K6: z_b = S_b @ x_b + c' 1^T (bf16 MFMA) -> zbf; per-block BN partials
// ---------------------------------------------------------------------------
__global__ __launch_bounds__(256) void z_mfma(
    const ushort* __restrict__ Sbf, const ushort* __restrict__ xT,
    const float* __restrict__ cprime, ushort* __restrict__ zbf,
    float* __restrict__ statsPart)
{
    __shared__ ushort As[128][40];
    __shared__ ushort Bs[128][40];
    __shared__ float cpL[128];
    __shared__ float sSum[2][128], sSq[2][128];
    const int t = threadIdx.x;
    const int n0 = blockIdx.x * 128, ct = blockIdx.y * 128, b = blockIdx.z;
    const int arow = t >> 1, ah = t & 1;
    const ushort* aSrc = Sbf + ((size_t)(b * CC + ct + arow)) * CC + ah * 16;
    const ushort* bSrc = xT + ((size_t)(b * NN + n0 + arow)) * CC + ah * 16;
    const int lane = t & 63, wid = t >> 6;
    const int mb = (wid >> 1) * 64, nb = (wid & 1) * 64;
    const int lm = lane & 15, q = lane >> 4;
    f32x4 acc[4][4] = {};

    if (t < 128) cpL[t] = cprime[b * CC + ct + t];

    for (int k0 = 0; k0 < CC; k0 += 32) {
        *(uint4*)&As[arow][ah * 16]     = ((const uint4*)(aSrc + k0))[0];
        *(uint4*)&As[arow][ah * 16 + 8] = ((const uint4*)(aSrc + k0))[1];
        *(uint4*)&Bs[arow][ah * 16]     = ((const uint4*)(bSrc + k0))[0];
        *(uint4*)&Bs[arow][ah * 16 + 8] = ((const uint4*)(bSrc + k0))[1];
        __syncthreads();
        bf16x8 af[4], bf[4];
        #pragma unroll
        for (int mt = 0; mt < 4; ++mt)
            af[mt] = *(const bf16x8*)&As[mb + mt * 16 + lm][q * 8];
        #pragma unroll
        for (int nt = 0; nt < 4; ++nt)
            bf[nt] = *(const bf16x8*)&Bs[nb + nt * 16 + lm][q * 8];
        #pragma unroll
        for (int mt = 0; mt < 4; ++mt)
            #pragma unroll
            for (int nt = 0; nt < 4; ++nt)
                acc[mt][nt] = __builtin_amdgcn_mfma_f32_16x16x32_bf16(af[mt], bf[nt], acc[mt][nt], 0, 0, 0);
        __syncthreads();
    }
    const int nbw = wid & 1;
    #pragma unroll
    for (int mt = 0; mt < 4; ++mt) {
        #pragma unroll
        for (int r = 0; r < 4; ++r) {
            const int cl = mb + mt * 16 + q * 4 + r;
            const int ci = ct + cl;
            const float cp = cpL[cl];
            const size_t zrow = ((size_t)(b * CC + ci)) * NN;
            float s1 = 0.f, q1 = 0.f;
            #pragma unroll
            for (int nt = 0; nt < 4; ++nt) {
                const float val = acc[mt][nt][r] + cp;
                const int tok = n0 + nb + nt * 16 + lm;
                zbf[zrow + tok] = f2bf(val);
                s1 += val; q1 += val * val;
            }
            #pragma unroll
            for (int m = 1; m < 16; m <<= 1) {
                s1 += __shfl_xor(s1, m);
                q1 += __shfl_xor(q1, m);
            }
            if (lm == 0) { sSum[nbw][cl] = s1; sSq[nbw][cl] = q1; }
        }
    }
    __syncthreads();
    if (t < 128) {
        const int slot = blockIdx.z * 16 + blockIdx.x;
        statsPart[(size_t)slot * 512 + ct + t]       = sSum[0][t] + sSum[1][t];
        statsPart[(size_t)slot * 512 + 256 + ct + t] = sSq[0][t] + sSq[1][t];
    }
}

// ---------------------------------------------------------------------------
// K7: finalize stats (vectorized, 4-way slot split)
// ---------------------------------------------------------------------------
__global__ __launch_bounds__(512) void bn_finalize(
    const float* __restrict__ statsPart, float* __restrict__ stats2)
{
    __shared__ float4 red4[4][128];
    __shared__ float sf[512];
    const int t = threadIdx.x, col = t & 127, grp = t >> 7;
    const float4* sp4 = (const float4*)statsPart;
    float4 a = { 0.f, 0.f, 0.f, 0.f };
    for (int s = grp; s < 256; s += 4) {
        float4 v = sp4[(size_t)s * 128 + col];
        a.x += v.x; a.y += v.y; a.z += v.z; a.w += v.w;
    }
    red4[grp][col] = a;
    __syncthreads();
    if (t < 128) {
        float4 t0 = red4[0][t], t1 = red4[1][t], t2 = red4[2][t], t3 = red4[3][t];
        sf[t*4+0] = t0.x + t1.x + t2.x + t3.x;
        sf[t*4+1] = t0.y + t1.y + t2.y + t3.y;
        sf[t*4+2] = t0.z + t1.z + t2.z + t3.z;
        sf[t*4+3] = t0.w + t1.w + t2.w + t3.w;
    }
    __syncthreads();
    if (t < 256) {
        const float cnt = (float)(BB * NN);
        const float mean = sf[t] / cnt;
        const float var = sf[256 + t] / cnt - mean * mean;
        stats2[t] = mean;
        stats2[CC + t] = rsqrtf(var + BN_EPS);
    }
}

// ---------------------------------------------------------------------------
// K8: out = (z - mean)*istd*gamma + beta + x
// ---------------------------------------------------------------------------
__global__ __launch_bounds__(256) void bn_apply(
    const ushort* __restrict__ zbf, const float* __restrict__ x,
    float* __restrict__ out, const float* __restrict__ stats2,
    const float* __restrict__ gamma, const float* __restrict__ beta)
{
    const size_t i = (size_t)blockIdx.x * 256 + threadIdx.x;
    const size_t base = i * 8;
    const int c = (int)((base >> 11) & (CC - 1));
    const float mean = stats2[c], istd = stats2[CC + c];
    const float gm = gamma[c] * istd;
    const float bt = beta[c] - mean * gm;
    const uint4 zz = *(const uint4*)(zbf + base);
    const float4 x0 = *(const float4*)(x + base);
    const float4 x1 = *(const float4*)(x + base + 4);
    float4 o0, o1;
    o0.x = bflo(zz.x) * gm + bt + x0.x;  o0.y = bfhi(zz.x) * gm + bt + x0.y;
    o0.z = bflo(zz.y) * gm + bt + x0.z;  o0.w = bfhi(zz.y) * gm + bt + x0.w;
    o1.x = bflo(zz.z) * gm + bt + x1.x;  o1.y = bfhi(zz.z) * gm + bt + x1.y;
    o1.z = bflo(zz.w) * gm + bt + x1.z;  o1.w = bfhi(zz.w) * gm + bt + x1.w;
    *(float4*)(out + base) = o0;
    *(float4*)(out + base + 4) = o1;
}

// ---------------------------------------------------------------------------
extern "C" void kernel_launch(void* const* d_in, const int* in_sizes, int n_in,
                              void* d_out, int out_size, void* d_ws, size_t ws_size,
                              hipStream_t stream) {
    const float* x    = (const float*)d_in[0];
    const float* g_w  = (const float*)d_in[1];
    const float* g_b  = (const float*)d_in[2];
    const float* th_w = (const float*)d_in[3];
    const float* th_b = (const float*)d_in[4];
    const float* ph_w = (const float*)d_in[5];
    const float* ph_b = (const float*)d_in[6];
    const float* W_w  = (const float*)d_in[7];
    // d_in[8] (W_b) cancels exactly in batch-norm
    const float* bn_g = (const float*)d_in[9];
    const float* bn_bt= (const float*)d_in[10];
    float* wsf = (float*)d_ws;
    float* out = (float*)d_out;
    ushort* ub = (ushort*)(wsf + OFF_FEND);

    gram_mfma<<<dim3(2, 2, 64), 256, 0, stream>>>(x, wsf + OFF_GPART, wsf + OFF_SPART);
    convert_xt<<<dim3(32, 4, 16), 256, 0, stream>>>(x, ub + UXT);
    gram_reduce<<<dim3(1024), 256, 0, stream>>>(wsf + OFF_GPART, ub + UGRAM);
    w1_kernel<<<dim3(33), 256, 0, stream>>>(W_w, g_w, ph_w, th_w, g_b, ph_b, th_b,
        ub + UE, ub + UFT, wsf + OFF_PT, wsf + OFF_R1, wsf + OFF_WGB, wsf + OFF_ALPHA);
    u_kernel<<<dim3(16), 256, 0, stream>>>(wsf + OFF_SPART, ub + UGRAM, ub + UE, ub + UFT,
        wsf + OFF_PT, wsf + OFF_R1, wsf + OFF_WGB, wsf + OFF_ALPHA,
        wsf + OFF_CP, wsf + OFF_L1, wsf + OFF_R2);
    h_mfma<<<dim3(2, 2, 16), 256, 0, stream>>>(ub + UFT, ub + UGRAM, ub + UHT);
    s2_mfma<<<dim3(2, 2, 16), 256, 0, stream>>>(ub + UE, ub + UHT,
        wsf + OFF_R1, wsf + OFF_R2, wsf + OFF_L1, wsf + OFF_WGB, ub + USBF);
    z_mfma<<<dim3(16, 2, 16), 256, 0, stream>>>(ub + USBF, ub + UXT,
        wsf + OFF_CP, ub + UZ, wsf + OFF_STATP);
    bn_finalize<<<dim3(1), 512, 0, stream>>>(wsf + OFF_STATP, wsf + OFF_STAT2);
    bn_apply<<<dim3(4096), 256, 0, stream>>>(ub + UZ, x, out, wsf + OFF_STAT2, bn_g, bn_bt);
}